// Round 4
// baseline (634.033 us; speedup 1.0000x reference)
//
#include <hip/hip_runtime.h>
#include <hip/hip_bf16.h>

#define S 128
#define R 384
#define CIN 256
#define H 8
#define D 32
#define CZ 128
#define E 256   // H*D

typedef __attribute__((ext_vector_type(8))) short short8;
typedef __attribute__((ext_vector_type(4))) short short4_;
typedef __attribute__((ext_vector_type(4))) float f32x4;
typedef __attribute__((ext_vector_type(4))) unsigned int u32x4;
typedef __attribute__((ext_vector_type(8))) _Float16 half8;

union U8 { short8 s; unsigned int u[4]; };

__device__ __forceinline__ unsigned short f2bs_u(float f) {
    __hip_bfloat16 h = __float2bfloat16(f);
    return *reinterpret_cast<unsigned short*>(&h);
}
__device__ __forceinline__ short f2bs(float f) {
    __hip_bfloat16 h = __float2bfloat16(f);
    return *reinterpret_cast<short*>(&h);
}
__device__ __forceinline__ float bs2f(unsigned short u) {
    union { unsigned int i; float f; } c;
    c.i = ((unsigned int)u) << 16;
    return c.f;
}
// fp16 bit helpers
__device__ __forceinline__ short f2hs(float f) {
    _Float16 h = (_Float16)f;
    return *reinterpret_cast<short*>(&h);
}
__device__ __forceinline__ float hs2f(unsigned short u) {
    _Float16 h = *reinterpret_cast<_Float16*>(&u);
    return (float)h;
}
// pack f32 -> (hi bf16 in low16, lo bf16 in high16)
__device__ __forceinline__ unsigned int packhl(float x) {
    unsigned short h = f2bs_u(x);
    float rem = x - bs2f(h);
    unsigned short l = f2bs_u(rem);
    return (unsigned int)h | ((unsigned int)l << 16);
}
// 4x4 transpose across 4 lanes (p = lane&3), regs x0..x3
__device__ __forceinline__ void xpose4(float& x0, float& x1, float& x2, float& x3, int p) {
    float tmp;
    if (p & 1) { tmp = x0; x0 = x1; x1 = tmp; tmp = x2; x2 = x3; x3 = tmp; }
    x1 = __shfl_xor(x1, 1); x3 = __shfl_xor(x3, 1);
    if (p & 1) { tmp = x0; x0 = x1; x1 = tmp; tmp = x2; x2 = x3; x3 = tmp; }
    if (p & 2) { tmp = x0; x0 = x2; x2 = tmp; tmp = x1; x1 = x3; x3 = tmp; }
    x2 = __shfl_xor(x2, 2); x3 = __shfl_xor(x3, 2);
    if (p & 2) { tmp = x0; x0 = x2; x2 = tmp; tmp = x1; x1 = x3; x3 = tmp; }
}

// ---------------------------------------------------------------------------
// K0: weight prep. Transpose to e-major and split into bf16 hi/lo. (round-1)
// blocks 0..255: wq/wk/wv/wg -> wt[mat][e][c]; blocks 256..319: wo -> wot[cout][e]
// ---------------------------------------------------------------------------
__global__ __launch_bounds__(256) void k_prepw(
    const float* __restrict__ wq, const float* __restrict__ wk,
    const float* __restrict__ wv, const float* __restrict__ wg,
    const float* __restrict__ wo,
    unsigned short* __restrict__ wt_hi, unsigned short* __restrict__ wt_lo,
    unsigned short* __restrict__ wot_hi, unsigned short* __restrict__ wot_lo)
{
    __shared__ float tl[32][36];
    const int b = blockIdx.x, t = threadIdx.x;
    const int iswo = (b >= 256);
    const int bb = iswo ? (b - 256) : (b & 63);
    const int te = bb >> 3, tc = bb & 7;
    const int mat = b >> 6;
    const float* src = iswo ? wo : (mat == 0 ? wq : mat == 1 ? wk : mat == 2 ? wv : wg);
    unsigned short* dh = iswo ? wot_hi : wt_hi + (size_t)mat * 65536;
    unsigned short* dl = iswo ? wot_lo : wt_lo + (size_t)mat * 65536;

    const int r = t >> 3, c4 = (t & 7) * 4;
    float4 v = *(const float4*)(src + (size_t)(tc * 32 + r) * 256 + te * 32 + c4);
    tl[r][c4] = v.x; tl[r][c4 + 1] = v.y; tl[r][c4 + 2] = v.z; tl[r][c4 + 3] = v.w;
    __syncthreads();
    short4_ hv, lv;
#pragma unroll
    for (int j = 0; j < 4; j++) {
        float x = tl[c4 + j][r];
        unsigned short hb = f2bs_u(x);
        hv[j] = (short)hb;
        lv[j] = f2bs(x - bs2f(hb));
    }
    size_t o = (size_t)(te * 32 + r) * 256 + tc * 32 + c4;
    *(short4_*)(dh + o) = hv;
    *(short4_*)(dl + o) = lv;
}

// ---------------------------------------------------------------------------
// K1: pair bias (f32, unchanged)
// ---------------------------------------------------------------------------
__global__ __launch_bounds__(256) void k_pairbias(
    const float* __restrict__ z, const float* __restrict__ lnw,
    const float* __restrict__ lnb, const float* __restrict__ wp,
    float* __restrict__ pb)
{
    int wid  = blockIdx.x * 4 + (threadIdx.x >> 6);
    int lane = threadIdx.x & 63;
    int qi = wid / R;
    int ki = wid - qi * R;
    const float* zr = z + (size_t)wid * CZ;
    float z0 = zr[lane], z1 = zr[lane + 64];
    float s  = z0 + z1;
    float sq = z0 * z0 + z1 * z1;
#pragma unroll
    for (int off = 32; off >= 1; off >>= 1) {
        s  += __shfl_xor(s, off);
        sq += __shfl_xor(sq, off);
    }
    float mu   = s * (1.0f / CZ);
    float var  = sq * (1.0f / CZ) - mu * mu;
    float rstd = rsqrtf(var + 1e-5f);
    float zl0 = (z0 - mu) * rstd * lnw[lane]      + lnb[lane];
    float zl1 = (z1 - mu) * rstd * lnw[lane + 64] + lnb[lane + 64];
    const float* w0 = wp + lane * H;
    const float* w1 = wp + (lane + 64) * H;
    float ph[H];
#pragma unroll
    for (int h = 0; h < H; h++) ph[h] = zl0 * w0[h] + zl1 * w1[h];
#pragma unroll
    for (int off = 32; off >= 1; off >>= 1) {
#pragma unroll
        for (int h = 0; h < H; h++) ph[h] += __shfl_xor(ph[h], off);
    }
    if (lane == 0) {
#pragma unroll
        for (int h = 0; h < H; h++)
            pb[((size_t)h * R + qi) * R + ki] = ph[h];
    }
}

// ---------------------------------------------------------------------------
// K2 v6: round-1 NUMERICS (A bf16 hi/lo, W bf16 hi/lo, 3 bf16 MFMAs, fp16
// output stores), restructured for occupancy: 512-thread blocks, 8 waves.
// Wave w2: matrix = w2&3, nc-half = w2>>2 (waves pair-split the 4 nc column
// groups -> same total instructions, disjoint B columns, 2x wave concurrency).
// LDS ~66.5 KB -> 2 blocks/CU = 16 waves/CU (vs round-1's 8).
// ---------------------------------------------------------------------------
__global__ __launch_bounds__(512, 4) void k_proj(
    const float* __restrict__ m, const float* __restrict__ lnw,
    const float* __restrict__ lnb,
    const unsigned short* __restrict__ wt_hi, const unsigned short* __restrict__ wt_lo,
    const float* __restrict__ bg,
    unsigned short* __restrict__ qb, unsigned short* __restrict__ kb,
    unsigned short* __restrict__ vtb, unsigned short* __restrict__ gb)
{
    __shared__ unsigned short Ah[64][264];
    __shared__ unsigned short Al[64][264];
    __shared__ float muv[64][2];
    const int t = threadIdx.x;
    const int row0 = blockIdx.x * 64;
    const int sblk = blockIdx.x / 6;
    const int res0 = (blockIdx.x % 6) * 64;

    // pass 1: LN stats, 2 threads per row (partners adjacent in wave)
    if (t < 128) {
        int r = t >> 1, half = t & 1;
        const float* mr = m + (size_t)(row0 + r) * CIN + half * 128;
        float s = 0.f, sq = 0.f;
#pragma unroll
        for (int i = 0; i < 32; i++) {
            f32x4 v = *(const f32x4*)(mr + i * 4);
#pragma unroll
            for (int q = 0; q < 4; q++) { s += v[q]; sq += v[q] * v[q]; }
        }
        s  += __shfl_xor(s, 1);
        sq += __shfl_xor(sq, 1);
        if (half == 0) {
            float mu  = s * (1.0f / CIN);
            float var = sq * (1.0f / CIN) - mu * mu;
            muv[r][0] = mu;
            muv[r][1] = rsqrtf(var + 1e-5f);
        }
    }
    __syncthreads();
    // pass 2: normalize + bf16 hi/lo -> LDS planes
#pragma unroll
    for (int i = 0; i < 8; i++) {
        int idx = i * 512 + t;
        int r = idx >> 6, c4 = (idx & 63) * 4;
        f32x4 v = *(const f32x4*)(m + (size_t)(row0 + r) * CIN + c4);
        float4 lw = *(const float4*)(lnw + c4);
        float4 lb = *(const float4*)(lnb + c4);
        float mu = muv[r][0], rs = muv[r][1];
        short4_ oh, ol;
#pragma unroll
        for (int j = 0; j < 4; j++) {
            float lwj = (j == 0) ? lw.x : (j == 1) ? lw.y : (j == 2) ? lw.z : lw.w;
            float lbj = (j == 0) ? lb.x : (j == 1) ? lb.y : (j == 2) ? lb.z : lb.w;
            float x = (v[j] - mu) * rs * lwj + lbj;
            unsigned short hb = f2bs_u(x);
            oh[j] = (short)hb;
            ol[j] = f2bs(x - bs2f(hb));
        }
        *(short4_*)&Ah[r][c4] = oh;
        *(short4_*)&Al[r][c4] = ol;
    }
    __syncthreads();

    const int w2 = t >> 6;           // 0..7
    const int mat = w2 & 3;          // which weight matrix
    const int nch = w2 >> 2;         // nc half: 0 -> nc{0,1}, 1 -> nc{2,3}
    const int lane = t & 63, ln = lane & 15, quad = lane >> 4;
    const unsigned short* Bh = wt_hi + (size_t)mat * 65536;
    const unsigned short* Bl = wt_lo + (size_t)mat * 65536;

    for (int nci = 0; nci < 2; nci++) {
        const int nc = nch * 2 + nci;
        const int nbase = nc * 64;
        f32x4 acc[4][4];
#pragma unroll
        for (int a = 0; a < 4; a++)
#pragma unroll
            for (int b = 0; b < 4; b++) acc[a][b] = (f32x4){0.f, 0.f, 0.f, 0.f};

#pragma unroll 2
        for (int kk = 0; kk < 8; kk++) {
            const int kcol = kk * 32 + quad * 8;
            short8 ah[4], al[4];
#pragma unroll
            for (int mt = 0; mt < 4; mt++) {
                ah[mt] = *(const short8*)&Ah[mt * 16 + ln][kcol];
                al[mt] = *(const short8*)&Al[mt * 16 + ln][kcol];
            }
#pragma unroll
            for (int nt = 0; nt < 4; nt++) {
                size_t boff = (size_t)(nbase + nt * 16 + ln) * 256 + kcol;
                short8 bh = *(const short8*)(Bh + boff);
                short8 bl = *(const short8*)(Bl + boff);
#pragma unroll
                for (int mt = 0; mt < 4; mt++) {
                    acc[mt][nt] = __builtin_amdgcn_mfma_f32_16x16x32_bf16(ah[mt], bh, acc[mt][nt], 0, 0, 0);
                    acc[mt][nt] = __builtin_amdgcn_mfma_f32_16x16x32_bf16(al[mt], bh, acc[mt][nt], 0, 0, 0);
                    acc[mt][nt] = __builtin_amdgcn_mfma_f32_16x16x32_bf16(ah[mt], bl, acc[mt][nt], 0, 0, 0);
                }
            }
        }
        // epilogue (outputs fp16)
        if (mat == 2) {
            // V: C-layout is res-contiguous per lane -> vt[h][d][res]
#pragma unroll
            for (int mt = 0; mt < 4; mt++) {
                int resg = res0 + mt * 16 + quad * 4;
#pragma unroll
                for (int nt = 0; nt < 4; nt++) {
                    int e = nbase + nt * 16 + ln;
                    int hh = e >> 5, d = e & 31;
                    f32x4 a = acc[mt][nt];
                    short4_ vv;
                    vv[0] = f2hs(a[0]); vv[1] = f2hs(a[1]);
                    vv[2] = f2hs(a[2]); vv[3] = f2hs(a[3]);
                    *(short4_*)(vtb + (((size_t)(sblk * H + hh)) * D + d) * R + resg) = vv;
                }
            }
        } else if (mat == 3) {
            const int p = ln & 3;
#pragma unroll
            for (int mt = 0; mt < 4; mt++) {
                int rowg = row0 + mt * 16 + quad * 4 + p;
#pragma unroll
                for (int nt = 0; nt < 4; nt++) {
                    int e0 = nbase + nt * 16 + (ln & 12);
                    f32x4 a = acc[mt][nt];
                    float x0 = a[0], x1 = a[1], x2 = a[2], x3 = a[3];
                    xpose4(x0, x1, x2, x3, p);
                    float4 bgv = *(const float4*)(bg + e0);
                    short4_ gv;
                    gv[0] = f2hs(1.0f / (1.0f + __expf(-(x0 + bgv.x))));
                    gv[1] = f2hs(1.0f / (1.0f + __expf(-(x1 + bgv.y))));
                    gv[2] = f2hs(1.0f / (1.0f + __expf(-(x2 + bgv.z))));
                    gv[3] = f2hs(1.0f / (1.0f + __expf(-(x3 + bgv.w))));
                    *(short4_*)(gb + (size_t)rowg * E + e0) = gv;
                }
            }
        } else {
            const float sc = (mat == 0) ? 0.17677669529663687f : 1.0f;
            unsigned short* dst = (mat == 0) ? qb : kb;
            const int p = ln & 3;
#pragma unroll
            for (int mt = 0; mt < 4; mt++) {
                int resg = res0 + mt * 16 + quad * 4 + p;
#pragma unroll
                for (int nt = 0; nt < 4; nt++) {
                    int e0 = nbase + nt * 16 + (ln & 12);
                    f32x4 a = acc[mt][nt];
                    float x0 = a[0] * sc, x1 = a[1] * sc, x2 = a[2] * sc, x3 = a[3] * sc;
                    xpose4(x0, x1, x2, x3, p);
                    int hh = e0 >> 5, d0 = e0 & 31;
                    short4_ vv;
                    vv[0] = f2hs(x0); vv[1] = f2hs(x1); vv[2] = f2hs(x2); vv[3] = f2hs(x3);
                    *(short4_*)(dst + (((size_t)(sblk * H + hh)) * R + resg) * D + d0) = vv;
                }
            }
        }
    }
}

// ---------------------------------------------------------------------------
// K3: MFMA attention — fp16 operands (q/k/v/P/g), f32 accum, f32 bias.
// Unchanged from round 1 (verified passing).
// ---------------------------------------------------------------------------
__global__ __launch_bounds__(256, 2) void k_attn(
    const unsigned short* __restrict__ qb, const unsigned short* __restrict__ kb,
    const unsigned short* __restrict__ vtb, const unsigned short* __restrict__ gb,
    const float* __restrict__ pb, const float* __restrict__ mask,
    float* __restrict__ og)
{
    __shared__ unsigned short Ks[R][40];
    __shared__ unsigned short Vt[D][392];
    __shared__ float Ps[4][16][100];
    const int t = threadIdx.x;
    const int s = blockIdx.x >> 3;
    const int h = blockIdx.x & 7;
    const size_t kvbase = (size_t)(s * H + h) * R * D;

#pragma unroll
    for (int i = 0; i < 6; i++) {
        int idx = i * 256 + t;
        int res = idx >> 2, d = (idx & 3) * 8;
        *(short8*)&Ks[res][d] = *(const short8*)(kb + kvbase + (size_t)res * D + d);
    }
#pragma unroll
    for (int i = 0; i < 6; i++) {
        int idx = i * 256 + t;
        int d = idx / 48, j = idx - d * 48;
        *(short8*)&Vt[d][j * 8] = *(const short8*)(vtb + kvbase + (size_t)d * R + j * 8);
    }
    __syncthreads();

    const int w = t >> 6;
    const int lane = t & 63;
    const int ln = lane & 15;
    const int quad = lane >> 4;
    float (*Pw)[100] = Ps[w];

    float mr[24];
#pragma unroll
    for (int tt = 0; tt < 24; tt++)
        mr[tt] = 1e9f * (mask[s * R + tt * 16 + ln] - 1.0f);

    for (int qt = 0; qt < 6; qt++) {
        const int q0 = w * 96 + qt * 16;
        half8 aq = *(const half8*)(qb + kvbase + (size_t)(q0 + ln) * D + quad * 8);
        const float* pbrow = pb + ((size_t)h * R + q0 + quad * 4) * R + ln;

        f32x4 acc[24];
#pragma unroll
        for (int tt = 0; tt < 24; tt++) {
            f32x4 c;
#pragma unroll
            for (int r = 0; r < 4; r++)
                c[r] = pbrow[(size_t)r * R + tt * 16] + mr[tt];
            half8 bk = *(const half8*)&Ks[tt * 16 + ln][quad * 8];
            acc[tt] = __builtin_amdgcn_mfma_f32_16x16x32_f16(aq, bk, c, 0, 0, 0);
        }
        float l[4];
#pragma unroll
        for (int r = 0; r < 4; r++) {
            float mx = acc[0][r];
#pragma unroll
            for (int tt = 1; tt < 24; tt++) mx = fmaxf(mx, acc[tt][r]);
            mx = fmaxf(mx, __shfl_xor(mx, 1));
            mx = fmaxf(mx, __shfl_xor(mx, 2));
            mx = fmaxf(mx, __shfl_xor(mx, 4));
            mx = fmaxf(mx, __shfl_xor(mx, 8));
            float sum = 0.f;
#pragma unroll
            for (int tt = 0; tt < 24; tt++) {
                float p = __expf(acc[tt][r] - mx);
                acc[tt][r] = p;
                sum += p;
            }
            sum += __shfl_xor(sum, 1);
            sum += __shfl_xor(sum, 2);
            sum += __shfl_xor(sum, 4);
            sum += __shfl_xor(sum, 8);
            l[r] = sum;
        }
        f32x4 o0 = {0.f, 0.f, 0.f, 0.f}, o1 = {0.f, 0.f, 0.f, 0.f};
        for (int cc = 0; cc < 4; cc++) {
#pragma unroll
            for (int tt6 = 0; tt6 < 6; tt6++) {
                int tt = cc * 6 + tt6;
#pragma unroll
                for (int r = 0; r < 4; r++)
                    Pw[quad * 4 + r][tt6 * 16 + ln] = acc[tt][r];
            }
#pragma unroll
            for (int kk = 0; kk < 3; kk++) {
                f32x4 plo = *(f32x4*)&Pw[ln][kk * 32 + quad * 8];
                f32x4 phi = *(f32x4*)&Pw[ln][kk * 32 + quad * 8 + 4];
                half8 ap;
#pragma unroll
                for (int j = 0; j < 4; j++) {
                    ap[j]     = (_Float16)plo[j];
                    ap[4 + j] = (_Float16)phi[j];
                }
                int kg = cc * 96 + kk * 32;
                half8 bv0 = *(const half8*)&Vt[ln][kg + quad * 8];
                half8 bv1 = *(const half8*)&Vt[16 + ln][kg + quad * 8];
                o0 = __builtin_amdgcn_mfma_f32_16x16x32_f16(ap, bv0, o0, 0, 0, 0);
                o1 = __builtin_amdgcn_mfma_f32_16x16x32_f16(ap, bv1, o1, 0, 0, 0);
            }
        }
#pragma unroll
        for (int r = 0; r < 4; r++) {
            int mrow = quad * 4 + r;
            int rw = s * R + q0 + mrow;
            float invl = 1.0f / l[r];
            size_t base = (size_t)rw * E + h * D;
            float g0 = hs2f(gb[base + ln]);
            float g1 = hs2f(gb[base + 16 + ln]);
            og[base + ln]      = o0[r] * invl * g0;
            og[base + 16 + ln] = o1[r] * invl * g1;
        }
    }
}

// ---------------------------------------------------------------------------
// K4: out = og @ wo + bo via split-bf16 MFMA (round-1, verified)
// ---------------------------------------------------------------------------
__global__ __launch_bounds__(256, 2) void k_outproj(
    const float* __restrict__ og, const unsigned short* __restrict__ wot_hi,
    const unsigned short* __restrict__ wot_lo, const float* __restrict__ bo,
    float* __restrict__ out)
{
    __shared__ unsigned int otb[64][260];
    const int t = threadIdx.x;
    const int row0 = blockIdx.x * 64;
#pragma unroll
    for (int i = 0; i < 16; i++) {
        int e4 = i * 256 + t;
        int r = e4 >> 6, c = (e4 & 63) * 4;
        f32x4 v = *(const f32x4*)(og + (size_t)(row0 + r) * E + c);
        u32x4 pk;
        pk[0] = packhl(v[0]); pk[1] = packhl(v[1]);
        pk[2] = packhl(v[2]); pk[3] = packhl(v[3]);
        *(u32x4*)&otb[r][c] = pk;
    }
    __syncthreads();

    const int w = t >> 6, lane = t & 63, ln = lane & 15, quad = lane >> 4;
    const int nbase = w * 64;
    f32x4 acc[4][4];
#pragma unroll
    for (int a = 0; a < 4; a++)
#pragma unroll
        for (int b = 0; b < 4; b++) acc[a][b] = (f32x4){0.f, 0.f, 0.f, 0.f};

    for (int kk = 0; kk < 8; kk++) {
        const int kcol = kk * 32 + quad * 8;
        short8 ah[4], al[4];
#pragma unroll
        for (int mt = 0; mt < 4; mt++) {
            const unsigned int* up = &otb[mt * 16 + ln][kcol];
            u32x4 u0 = *(const u32x4*)up;
            u32x4 u1 = *(const u32x4*)(up + 4);
            U8 A, L;
            A.u[0] = (u0[0] & 0xffffu) | (u0[1] << 16);
            A.u[1] = (u0[2] & 0xffffu) | (u0[3] << 16);
            A.u[2] = (u1[0] & 0xffffu) | (u1[1] << 16);
            A.u[3] = (u1[2] & 0xffffu) | (u1[3] << 16);
            L.u[0] = (u0[0] >> 16) | (u0[1] & 0xffff0000u);
            L.u[1] = (u0[2] >> 16) | (u0[3] & 0xffff0000u);
            L.u[2] = (u1[0] >> 16) | (u1[1] & 0xffff0000u);
            L.u[3] = (u1[2] >> 16) | (u1[3] & 0xffff0000u);
            ah[mt] = A.s; al[mt] = L.s;
        }
#pragma unroll
        for (int nt = 0; nt < 4; nt++) {
            size_t boff = (size_t)(nbase + nt * 16 + ln) * 256 + kcol;
            short8 bh = *(const short8*)(wot_hi + boff);
            short8 bl = *(const short8*)(wot_lo + boff);
#pragma unroll
            for (int mt = 0; mt < 4; mt++) {
                acc[mt][nt] = __builtin_amdgcn_mfma_f32_16x16x32_bf16(ah[mt], bh, acc[mt][nt], 0, 0, 0);
                acc[mt][nt] = __builtin_amdgcn_mfma_f32_16x16x32_bf16(al[mt], bh, acc[mt][nt], 0, 0, 0);
                acc[mt][nt] = __builtin_amdgcn_mfma_f32_16x16x32_bf16(ah[mt], bl, acc[mt][nt], 0, 0, 0);
            }
        }
    }
    const int p = ln & 3;
#pragma unroll
    for (int mt = 0; mt < 4; mt++) {
        int rowg = row0 + mt * 16 + quad * 4 + p;
#pragma unroll
        for (int nt = 0; nt < 4; nt++) {
            int c0 = nbase + nt * 16 + (ln & 12);
            f32x4 a = acc[mt][nt];
            float x0 = a[0], x1 = a[1], x2 = a[2], x3 = a[3];
            xpose4(x0, x1, x2, x3, p);
            float4 bov = *(const float4*)(bo + c0);
            f32x4 o;
            o[0] = x0 + bov.x; o[1] = x1 + bov.y;
            o[2] = x2 + bov.z; o[3] = x3 + bov.w;
            *(f32x4*)(out + (size_t)rowg * CIN + c0) = o;
        }
    }
}

// ---------------------------------------------------------------------------
extern "C" void kernel_launch(void* const* d_in, const int* in_sizes, int n_in,
                              void* d_out, int out_size, void* d_ws, size_t ws_size,
                              hipStream_t stream)
{
    const float* m      = (const float*)d_in[0];
    const float* z      = (const float*)d_in[1];
    const float* mask   = (const float*)d_in[2];
    const float* ln_m_w = (const float*)d_in[3];
    const float* ln_m_b = (const float*)d_in[4];
    const float* ln_z_w = (const float*)d_in[5];
    const float* ln_z_b = (const float*)d_in[6];
    const float* w_pair = (const float*)d_in[7];
    const float* wq     = (const float*)d_in[8];
    const float* wk     = (const float*)d_in[9];
    const float* wv     = (const float*)d_in[10];
    const float* wg     = (const float*)d_in[11];
    const float* bg     = (const float*)d_in[12];
    const float* wo     = (const float*)d_in[13];
    const float* bo     = (const float*)d_in[14];
    float* out = (float*)d_out;

    char* ws = (char*)d_ws;
    float*          pbuf   = (float*)ws;              ws += 4718592;
    unsigned short* qb     = (unsigned short*)ws;     ws += 25165824;
    unsigned short* kb     = (unsigned short*)ws;     ws += 25165824;
    unsigned short* vtb    = (unsigned short*)ws;     ws += 25165824;
    unsigned short* gbuf   = (unsigned short*)ws;     ws += 25165824;
    float*          ogb    = (float*)ws;              ws += 50331648;
    unsigned short* wt_hi  = (unsigned short*)ws;     ws += 524288;
    unsigned short* wt_lo  = (unsigned short*)ws;     ws += 524288;
    unsigned short* wot_hi = (unsigned short*)ws;     ws += 131072;
    unsigned short* wot_lo = (unsigned short*)ws;     ws += 131072;

    k_prepw<<<dim3(320), dim3(256), 0, stream>>>(wq, wk, wv, wg, wo,
                                                 wt_hi, wt_lo, wot_hi, wot_lo);
    k_pairbias<<<dim3(R * R / 4), dim3(256), 0, stream>>>(z, ln_z_w, ln_z_b, w_pair, pbuf);
    k_proj<<<dim3(768), dim3(512), 0, stream>>>(m, ln_m_w, ln_m_b,
                                                wt_hi, wt_lo, bg, qb, kb, vtb, gbuf);
    k_attn<<<dim3(S * H), dim3(256), 0, stream>>>(qb, kb, vtb, gbuf, pbuf, mask, ogb);
    k_outproj<<<dim3(768), dim3(256), 0, stream>>>(ogb, wot_hi, wot_lo, bo, out);
}

// Round 5
// 629.001 us; speedup vs baseline: 1.0080x; 1.0080x over previous
//
#include <hip/hip_runtime.h>
#include <hip/hip_bf16.h>

#define S 128
#define R 384
#define CIN 256
#define H 8
#define D 32
#define CZ 128
#define E 256   // H*D

typedef __attribute__((ext_vector_type(8))) short short8;
typedef __attribute__((ext_vector_type(4))) short short4_;
typedef __attribute__((ext_vector_type(4))) float f32x4;
typedef __attribute__((ext_vector_type(4))) unsigned int u32x4;
typedef __attribute__((ext_vector_type(8))) _Float16 half8;

union U8 { short8 s; unsigned int u[4]; };

__device__ __forceinline__ unsigned short f2bs_u(float f) {
    __hip_bfloat16 h = __float2bfloat16(f);
    return *reinterpret_cast<unsigned short*>(&h);
}
__device__ __forceinline__ short f2bs(float f) {
    __hip_bfloat16 h = __float2bfloat16(f);
    return *reinterpret_cast<short*>(&h);
}
__device__ __forceinline__ float bs2f(unsigned short u) {
    union { unsigned int i; float f; } c;
    c.i = ((unsigned int)u) << 16;
    return c.f;
}
// fp16 bit helpers
__device__ __forceinline__ short f2hs(float f) {
    _Float16 h = (_Float16)f;
    return *reinterpret_cast<short*>(&h);
}
__device__ __forceinline__ float hs2f(unsigned short u) {
    _Float16 h = *reinterpret_cast<_Float16*>(&u);
    return (float)h;
}
// pack f32 -> (hi bf16 in low16, lo bf16 in high16)
__device__ __forceinline__ unsigned int packhl(float x) {
    unsigned short h = f2bs_u(x);
    float rem = x - bs2f(h);
    unsigned short l = f2bs_u(rem);
    return (unsigned int)h | ((unsigned int)l << 16);
}
// 4x4 transpose across 4 lanes (p = lane&3), regs x0..x3
__device__ __forceinline__ void xpose4(float& x0, float& x1, float& x2, float& x3, int p) {
    float tmp;
    if (p & 1) { tmp = x0; x0 = x1; x1 = tmp; tmp = x2; x2 = x3; x3 = tmp; }
    x1 = __shfl_xor(x1, 1); x3 = __shfl_xor(x3, 1);
    if (p & 1) { tmp = x0; x0 = x1; x1 = tmp; tmp = x2; x2 = x3; x3 = tmp; }
    if (p & 2) { tmp = x0; x0 = x2; x2 = tmp; tmp = x1; x1 = x3; x3 = tmp; }
    x2 = __shfl_xor(x2, 2); x3 = __shfl_xor(x3, 2);
    if (p & 2) { tmp = x0; x0 = x2; x2 = tmp; tmp = x1; x1 = x3; x3 = tmp; }
}

// ---------------------------------------------------------------------------
// K0: weight prep. Transpose to e-major and split into bf16 hi/lo. (round-1)
// blocks 0..255: wq/wk/wv/wg -> wt[mat][e][c]; blocks 256..319: wo -> wot[cout][e]
// ---------------------------------------------------------------------------
__global__ __launch_bounds__(256) void k_prepw(
    const float* __restrict__ wq, const float* __restrict__ wk,
    const float* __restrict__ wv, const float* __restrict__ wg,
    const float* __restrict__ wo,
    unsigned short* __restrict__ wt_hi, unsigned short* __restrict__ wt_lo,
    unsigned short* __restrict__ wot_hi, unsigned short* __restrict__ wot_lo)
{
    __shared__ float tl[32][36];
    const int b = blockIdx.x, t = threadIdx.x;
    const int iswo = (b >= 256);
    const int bb = iswo ? (b - 256) : (b & 63);
    const int te = bb >> 3, tc = bb & 7;
    const int mat = b >> 6;
    const float* src = iswo ? wo : (mat == 0 ? wq : mat == 1 ? wk : mat == 2 ? wv : wg);
    unsigned short* dh = iswo ? wot_hi : wt_hi + (size_t)mat * 65536;
    unsigned short* dl = iswo ? wot_lo : wt_lo + (size_t)mat * 65536;

    const int r = t >> 3, c4 = (t & 7) * 4;
    float4 v = *(const float4*)(src + (size_t)(tc * 32 + r) * 256 + te * 32 + c4);
    tl[r][c4] = v.x; tl[r][c4 + 1] = v.y; tl[r][c4 + 2] = v.z; tl[r][c4 + 3] = v.w;
    __syncthreads();
    short4_ hv, lv;
#pragma unroll
    for (int j = 0; j < 4; j++) {
        float x = tl[c4 + j][r];
        unsigned short hb = f2bs_u(x);
        hv[j] = (short)hb;
        lv[j] = f2bs(x - bs2f(hb));
    }
    size_t o = (size_t)(te * 32 + r) * 256 + tc * 32 + c4;
    *(short4_*)(dh + o) = hv;
    *(short4_*)(dl + o) = lv;
}

// ---------------------------------------------------------------------------
// K1: pair bias (f32, unchanged)
// ---------------------------------------------------------------------------
__global__ __launch_bounds__(256) void k_pairbias(
    const float* __restrict__ z, const float* __restrict__ lnw,
    const float* __restrict__ lnb, const float* __restrict__ wp,
    float* __restrict__ pb)
{
    int wid  = blockIdx.x * 4 + (threadIdx.x >> 6);
    int lane = threadIdx.x & 63;
    int qi = wid / R;
    int ki = wid - qi * R;
    const float* zr = z + (size_t)wid * CZ;
    float z0 = zr[lane], z1 = zr[lane + 64];
    float s  = z0 + z1;
    float sq = z0 * z0 + z1 * z1;
#pragma unroll
    for (int off = 32; off >= 1; off >>= 1) {
        s  += __shfl_xor(s, off);
        sq += __shfl_xor(sq, off);
    }
    float mu   = s * (1.0f / CZ);
    float var  = sq * (1.0f / CZ) - mu * mu;
    float rstd = rsqrtf(var + 1e-5f);
    float zl0 = (z0 - mu) * rstd * lnw[lane]      + lnb[lane];
    float zl1 = (z1 - mu) * rstd * lnw[lane + 64] + lnb[lane + 64];
    const float* w0 = wp + lane * H;
    const float* w1 = wp + (lane + 64) * H;
    float ph[H];
#pragma unroll
    for (int h = 0; h < H; h++) ph[h] = zl0 * w0[h] + zl1 * w1[h];
#pragma unroll
    for (int off = 32; off >= 1; off >>= 1) {
#pragma unroll
        for (int h = 0; h < H; h++) ph[h] += __shfl_xor(ph[h], off);
    }
    if (lane == 0) {
#pragma unroll
        for (int h = 0; h < H; h++)
            pb[((size_t)h * R + qi) * R + ki] = ph[h];
    }
}

// ---------------------------------------------------------------------------
// K2 v7: round-1 NUMERICS (A bf16 hi/lo, W bf16 hi/lo, 3 bf16 MFMAs, fp16
// output stores), 32-row A tile: LDS 34 KB -> 4 blocks/CU (16 waves/CU),
// 256 threads, acc[2][4] keeps VGPR well under the 128 cap (no spill —
// round-4 lesson: 512-thread/LB(512,4) forced VGPR=64 and spilled 280 MB).
// ---------------------------------------------------------------------------
__global__ __launch_bounds__(256, 4) void k_proj(
    const float* __restrict__ m, const float* __restrict__ lnw,
    const float* __restrict__ lnb,
    const unsigned short* __restrict__ wt_hi, const unsigned short* __restrict__ wt_lo,
    const float* __restrict__ bg,
    unsigned short* __restrict__ qb, unsigned short* __restrict__ kb,
    unsigned short* __restrict__ vtb, unsigned short* __restrict__ gb)
{
    __shared__ unsigned short Ah[32][264];
    __shared__ unsigned short Al[32][264];
    __shared__ float muv[32][2];
    const int t = threadIdx.x;
    const int row0 = blockIdx.x * 32;
    const int sblk = blockIdx.x / 12;
    const int res0 = (blockIdx.x % 12) * 32;

    // pass 1: LN stats, 2 threads per row (partners adjacent in wave 0)
    if (t < 64) {
        int r = t >> 1, half = t & 1;
        const float* mr = m + (size_t)(row0 + r) * CIN + half * 128;
        float s = 0.f, sq = 0.f;
#pragma unroll
        for (int i = 0; i < 32; i++) {
            f32x4 v = *(const f32x4*)(mr + i * 4);
#pragma unroll
            for (int q = 0; q < 4; q++) { s += v[q]; sq += v[q] * v[q]; }
        }
        s  += __shfl_xor(s, 1);
        sq += __shfl_xor(sq, 1);
        if (half == 0) {
            float mu  = s * (1.0f / CIN);
            float var = sq * (1.0f / CIN) - mu * mu;
            muv[r][0] = mu;
            muv[r][1] = rsqrtf(var + 1e-5f);
        }
    }
    __syncthreads();
    // pass 2: normalize + bf16 hi/lo -> LDS planes (32 rows x 64 c4-groups)
#pragma unroll
    for (int i = 0; i < 8; i++) {
        int idx = i * 256 + t;
        int r = idx >> 6, c4 = (idx & 63) * 4;
        f32x4 v = *(const f32x4*)(m + (size_t)(row0 + r) * CIN + c4);
        float4 lw = *(const float4*)(lnw + c4);
        float4 lb = *(const float4*)(lnb + c4);
        float mu = muv[r][0], rs = muv[r][1];
        short4_ oh, ol;
#pragma unroll
        for (int j = 0; j < 4; j++) {
            float lwj = (j == 0) ? lw.x : (j == 1) ? lw.y : (j == 2) ? lw.z : lw.w;
            float lbj = (j == 0) ? lb.x : (j == 1) ? lb.y : (j == 2) ? lb.z : lb.w;
            float x = (v[j] - mu) * rs * lwj + lbj;
            unsigned short hb = f2bs_u(x);
            oh[j] = (short)hb;
            ol[j] = f2bs(x - bs2f(hb));
        }
        *(short4_*)&Ah[r][c4] = oh;
        *(short4_*)&Al[r][c4] = ol;
    }
    __syncthreads();

    const int w = t >> 6, lane = t & 63, ln = lane & 15, quad = lane >> 4;
    const unsigned short* Bh = wt_hi + (size_t)w * 65536;
    const unsigned short* Bl = wt_lo + (size_t)w * 65536;

    for (int nc = 0; nc < 4; nc++) {
        const int nbase = nc * 64;
        f32x4 acc[2][4];
#pragma unroll
        for (int a = 0; a < 2; a++)
#pragma unroll
            for (int b = 0; b < 4; b++) acc[a][b] = (f32x4){0.f, 0.f, 0.f, 0.f};

#pragma unroll 2
        for (int kk = 0; kk < 8; kk++) {
            const int kcol = kk * 32 + quad * 8;
            short8 ah[2], al[2];
#pragma unroll
            for (int mt = 0; mt < 2; mt++) {
                ah[mt] = *(const short8*)&Ah[mt * 16 + ln][kcol];
                al[mt] = *(const short8*)&Al[mt * 16 + ln][kcol];
            }
#pragma unroll
            for (int nt = 0; nt < 4; nt++) {
                size_t boff = (size_t)(nbase + nt * 16 + ln) * 256 + kcol;
                short8 bh = *(const short8*)(Bh + boff);
                short8 bl = *(const short8*)(Bl + boff);
#pragma unroll
                for (int mt = 0; mt < 2; mt++) {
                    acc[mt][nt] = __builtin_amdgcn_mfma_f32_16x16x32_bf16(ah[mt], bh, acc[mt][nt], 0, 0, 0);
                    acc[mt][nt] = __builtin_amdgcn_mfma_f32_16x16x32_bf16(al[mt], bh, acc[mt][nt], 0, 0, 0);
                    acc[mt][nt] = __builtin_amdgcn_mfma_f32_16x16x32_bf16(ah[mt], bl, acc[mt][nt], 0, 0, 0);
                }
            }
        }
        // epilogue (outputs fp16)
        if (w == 2) {
            // V: C-layout is res-contiguous per lane -> vt[h][d][res]
#pragma unroll
            for (int mt = 0; mt < 2; mt++) {
                int resg = res0 + mt * 16 + quad * 4;
#pragma unroll
                for (int nt = 0; nt < 4; nt++) {
                    int e = nbase + nt * 16 + ln;
                    int hh = e >> 5, d = e & 31;
                    f32x4 a = acc[mt][nt];
                    short4_ vv;
                    vv[0] = f2hs(a[0]); vv[1] = f2hs(a[1]);
                    vv[2] = f2hs(a[2]); vv[3] = f2hs(a[3]);
                    *(short4_*)(vtb + (((size_t)(sblk * H + hh)) * D + d) * R + resg) = vv;
                }
            }
        } else if (w == 3) {
            const int p = ln & 3;
#pragma unroll
            for (int mt = 0; mt < 2; mt++) {
                int rowg = row0 + mt * 16 + quad * 4 + p;
#pragma unroll
                for (int nt = 0; nt < 4; nt++) {
                    int e0 = nbase + nt * 16 + (ln & 12);
                    f32x4 a = acc[mt][nt];
                    float x0 = a[0], x1 = a[1], x2 = a[2], x3 = a[3];
                    xpose4(x0, x1, x2, x3, p);
                    float4 bgv = *(const float4*)(bg + e0);
                    short4_ gv;
                    gv[0] = f2hs(1.0f / (1.0f + __expf(-(x0 + bgv.x))));
                    gv[1] = f2hs(1.0f / (1.0f + __expf(-(x1 + bgv.y))));
                    gv[2] = f2hs(1.0f / (1.0f + __expf(-(x2 + bgv.z))));
                    gv[3] = f2hs(1.0f / (1.0f + __expf(-(x3 + bgv.w))));
                    *(short4_*)(gb + (size_t)rowg * E + e0) = gv;
                }
            }
        } else {
            const float sc = (w == 0) ? 0.17677669529663687f : 1.0f;
            unsigned short* dst = (w == 0) ? qb : kb;
            const int p = ln & 3;
#pragma unroll
            for (int mt = 0; mt < 2; mt++) {
                int resg = res0 + mt * 16 + quad * 4 + p;
#pragma unroll
                for (int nt = 0; nt < 4; nt++) {
                    int e0 = nbase + nt * 16 + (ln & 12);
                    f32x4 a = acc[mt][nt];
                    float x0 = a[0] * sc, x1 = a[1] * sc, x2 = a[2] * sc, x3 = a[3] * sc;
                    xpose4(x0, x1, x2, x3, p);
                    int hh = e0 >> 5, d0 = e0 & 31;
                    short4_ vv;
                    vv[0] = f2hs(x0); vv[1] = f2hs(x1); vv[2] = f2hs(x2); vv[3] = f2hs(x3);
                    *(short4_*)(dst + (((size_t)(sblk * H + hh)) * R + resg) * D + d0) = vv;
                }
            }
        }
    }
}

// ---------------------------------------------------------------------------
// K3: MFMA attention — fp16 operands (q/k/v/P/g), f32 accum, f32 bias.
// Unchanged (verified passing).
// ---------------------------------------------------------------------------
__global__ __launch_bounds__(256, 2) void k_attn(
    const unsigned short* __restrict__ qb, const unsigned short* __restrict__ kb,
    const unsigned short* __restrict__ vtb, const unsigned short* __restrict__ gb,
    const float* __restrict__ pb, const float* __restrict__ mask,
    float* __restrict__ og)
{
    __shared__ unsigned short Ks[R][40];
    __shared__ unsigned short Vt[D][392];
    __shared__ float Ps[4][16][100];
    const int t = threadIdx.x;
    const int s = blockIdx.x >> 3;
    const int h = blockIdx.x & 7;
    const size_t kvbase = (size_t)(s * H + h) * R * D;

#pragma unroll
    for (int i = 0; i < 6; i++) {
        int idx = i * 256 + t;
        int res = idx >> 2, d = (idx & 3) * 8;
        *(short8*)&Ks[res][d] = *(const short8*)(kb + kvbase + (size_t)res * D + d);
    }
#pragma unroll
    for (int i = 0; i < 6; i++) {
        int idx = i * 256 + t;
        int d = idx / 48, j = idx - d * 48;
        *(short8*)&Vt[d][j * 8] = *(const short8*)(vtb + kvbase + (size_t)d * R + j * 8);
    }
    __syncthreads();

    const int w = t >> 6;
    const int lane = t & 63;
    const int ln = lane & 15;
    const int quad = lane >> 4;
    float (*Pw)[100] = Ps[w];

    float mr[24];
#pragma unroll
    for (int tt = 0; tt < 24; tt++)
        mr[tt] = 1e9f * (mask[s * R + tt * 16 + ln] - 1.0f);

    for (int qt = 0; qt < 6; qt++) {
        const int q0 = w * 96 + qt * 16;
        half8 aq = *(const half8*)(qb + kvbase + (size_t)(q0 + ln) * D + quad * 8);
        const float* pbrow = pb + ((size_t)h * R + q0 + quad * 4) * R + ln;

        f32x4 acc[24];
#pragma unroll
        for (int tt = 0; tt < 24; tt++) {
            f32x4 c;
#pragma unroll
            for (int r = 0; r < 4; r++)
                c[r] = pbrow[(size_t)r * R + tt * 16] + mr[tt];
            half8 bk = *(const half8*)&Ks[tt * 16 + ln][quad * 8];
            acc[tt] = __builtin_amdgcn_mfma_f32_16x16x32_f16(aq, bk, c, 0, 0, 0);
        }
        float l[4];
#pragma unroll
        for (int r = 0; r < 4; r++) {
            float mx = acc[0][r];
#pragma unroll
            for (int tt = 1; tt < 24; tt++) mx = fmaxf(mx, acc[tt][r]);
            mx = fmaxf(mx, __shfl_xor(mx, 1));
            mx = fmaxf(mx, __shfl_xor(mx, 2));
            mx = fmaxf(mx, __shfl_xor(mx, 4));
            mx = fmaxf(mx, __shfl_xor(mx, 8));
            float sum = 0.f;
#pragma unroll
            for (int tt = 0; tt < 24; tt++) {
                float p = __expf(acc[tt][r] - mx);
                acc[tt][r] = p;
                sum += p;
            }
            sum += __shfl_xor(sum, 1);
            sum += __shfl_xor(sum, 2);
            sum += __shfl_xor(sum, 4);
            sum += __shfl_xor(sum, 8);
            l[r] = sum;
        }
        f32x4 o0 = {0.f, 0.f, 0.f, 0.f}, o1 = {0.f, 0.f, 0.f, 0.f};
        for (int cc = 0; cc < 4; cc++) {
#pragma unroll
            for (int tt6 = 0; tt6 < 6; tt6++) {
                int tt = cc * 6 + tt6;
#pragma unroll
                for (int r = 0; r < 4; r++)
                    Pw[quad * 4 + r][tt6 * 16 + ln] = acc[tt][r];
            }
#pragma unroll
            for (int kk = 0; kk < 3; kk++) {
                f32x4 plo = *(f32x4*)&Pw[ln][kk * 32 + quad * 8];
                f32x4 phi = *(f32x4*)&Pw[ln][kk * 32 + quad * 8 + 4];
                half8 ap;
#pragma unroll
                for (int j = 0; j < 4; j++) {
                    ap[j]     = (_Float16)plo[j];
                    ap[4 + j] = (_Float16)phi[j];
                }
                int kg = cc * 96 + kk * 32;
                half8 bv0 = *(const half8*)&Vt[ln][kg + quad * 8];
                half8 bv1 = *(const half8*)&Vt[16 + ln][kg + quad * 8];
                o0 = __builtin_amdgcn_mfma_f32_16x16x32_f16(ap, bv0, o0, 0, 0, 0);
                o1 = __builtin_amdgcn_mfma_f32_16x16x32_f16(ap, bv1, o1, 0, 0, 0);
            }
        }
#pragma unroll
        for (int r = 0; r < 4; r++) {
            int mrow = quad * 4 + r;
            int rw = s * R + q0 + mrow;
            float invl = 1.0f / l[r];
            size_t base = (size_t)rw * E + h * D;
            float g0 = hs2f(gb[base + ln]);
            float g1 = hs2f(gb[base + 16 + ln]);
            og[base + ln]      = o0[r] * invl * g0;
            og[base + 16 + ln] = o1[r] * invl * g1;
        }
    }
}

// ---------------------------------------------------------------------------
// K4: out = og @ wo + bo via split-bf16 MFMA (round-1, verified)
// ---------------------------------------------------------------------------
__global__ __launch_bounds__(256, 2) void k_outproj(
    const float* __restrict__ og, const unsigned short* __restrict__ wot_hi,
    const unsigned short* __restrict__ wot_lo, const float* __restrict__ bo,
    float* __restrict__ out)
{
    __shared__ unsigned int otb[64][260];
    const int t = threadIdx.x;
    const int row0 = blockIdx.x * 64;
#pragma unroll
    for (int i = 0; i < 16; i++) {
        int e4 = i * 256 + t;
        int r = e4 >> 6, c = (e4 & 63) * 4;
        f32x4 v = *(const f32x4*)(og + (size_t)(row0 + r) * E + c);
        u32x4 pk;
        pk[0] = packhl(v[0]); pk[1] = packhl(v[1]);
        pk[2] = packhl(v[2]); pk[3] = packhl(v[3]);
        *(u32x4*)&otb[r][c] = pk;
    }
    __syncthreads();

    const int w = t >> 6, lane = t & 63, ln = lane & 15, quad = lane >> 4;
    const int nbase = w * 64;
    f32x4 acc[4][4];
#pragma unroll
    for (int a = 0; a < 4; a++)
#pragma unroll
        for (int b = 0; b < 4; b++) acc[a][b] = (f32x4){0.f, 0.f, 0.f, 0.f};

    for (int kk = 0; kk < 8; kk++) {
        const int kcol = kk * 32 + quad * 8;
        short8 ah[4], al[4];
#pragma unroll
        for (int mt = 0; mt < 4; mt++) {
            const unsigned int* up = &otb[mt * 16 + ln][kcol];
            u32x4 u0 = *(const u32x4*)up;
            u32x4 u1 = *(const u32x4*)(up + 4);
            U8 A, L;
            A.u[0] = (u0[0] & 0xffffu) | (u0[1] << 16);
            A.u[1] = (u0[2] & 0xffffu) | (u0[3] << 16);
            A.u[2] = (u1[0] & 0xffffu) | (u1[1] << 16);
            A.u[3] = (u1[2] & 0xffffu) | (u1[3] << 16);
            L.u[0] = (u0[0] >> 16) | (u0[1] & 0xffff0000u);
            L.u[1] = (u0[2] >> 16) | (u0[3] & 0xffff0000u);
            L.u[2] = (u1[0] >> 16) | (u1[1] & 0xffff0000u);
            L.u[3] = (u1[2] >> 16) | (u1[3] & 0xffff0000u);
            ah[mt] = A.s; al[mt] = L.s;
        }
#pragma unroll
        for (int nt = 0; nt < 4; nt++) {
            size_t boff = (size_t)(nbase + nt * 16 + ln) * 256 + kcol;
            short8 bh = *(const short8*)(wot_hi + boff);
            short8 bl = *(const short8*)(wot_lo + boff);
#pragma unroll
            for (int mt = 0; mt < 4; mt++) {
                acc[mt][nt] = __builtin_amdgcn_mfma_f32_16x16x32_bf16(ah[mt], bh, acc[mt][nt], 0, 0, 0);
                acc[mt][nt] = __builtin_amdgcn_mfma_f32_16x16x32_bf16(al[mt], bh, acc[mt][nt], 0, 0, 0);
                acc[mt][nt] = __builtin_amdgcn_mfma_f32_16x16x32_bf16(ah[mt], bl, acc[mt][nt], 0, 0, 0);
            }
        }
    }
    const int p = ln & 3;
#pragma unroll
    for (int mt = 0; mt < 4; mt++) {
        int rowg = row0 + mt * 16 + quad * 4 + p;
#pragma unroll
        for (int nt = 0; nt < 4; nt++) {
            int c0 = nbase + nt * 16 + (ln & 12);
            f32x4 a = acc[mt][nt];
            float x0 = a[0], x1 = a[1], x2 = a[2], x3 = a[3];
            xpose4(x0, x1, x2, x3, p);
            float4 bov = *(const float4*)(bo + c0);
            f32x4 o;
            o[0] = x0 + bov.x; o[1] = x1 + bov.y;
            o[2] = x2 + bov.z; o[3] = x3 + bov.w;
            *(f32x4*)(out + (size_t)rowg * CIN + c0) = o;
        }
    }
}

// ---------------------------------------------------------------------------
extern "C" void kernel_launch(void* const* d_in, const int* in_sizes, int n_in,
                              void* d_out, int out_size, void* d_ws, size_t ws_size,
                              hipStream_t stream)
{
    const float* m      = (const float*)d_in[0];
    const float* z      = (const float*)d_in[1];
    const float* mask   = (const float*)d_in[2];
    const float* ln_m_w = (const float*)d_in[3];
    const float* ln_m_b = (const float*)d_in[4];
    const float* ln_z_w = (const float*)d_in[5];
    const float* ln_z_b = (const float*)d_in[6];
    const float* w_pair = (const float*)d_in[7];
    const float* wq     = (const float*)d_in[8];
    const float* wk     = (const float*)d_in[9];
    const float* wv     = (const float*)d_in[10];
    const float* wg     = (const float*)d_in[11];
    const float* bg     = (const float*)d_in[12];
    const float* wo     = (const float*)d_in[13];
    const float* bo     = (const float*)d_in[14];
    float* out = (float*)d_out;

    char* ws = (char*)d_ws;
    float*          pbuf   = (float*)ws;              ws += 4718592;
    unsigned short* qb     = (unsigned short*)ws;     ws += 25165824;
    unsigned short* kb     = (unsigned short*)ws;     ws += 25165824;
    unsigned short* vtb    = (unsigned short*)ws;     ws += 25165824;
    unsigned short* gbuf   = (unsigned short*)ws;     ws += 25165824;
    float*          ogb    = (float*)ws;              ws += 50331648;
    unsigned short* wt_hi  = (unsigned short*)ws;     ws += 524288;
    unsigned short* wt_lo  = (unsigned short*)ws;     ws += 524288;
    unsigned short* wot_hi = (unsigned short*)ws;     ws += 131072;
    unsigned short* wot_lo = (unsigned short*)ws;     ws += 131072;

    k_prepw<<<dim3(320), dim3(256), 0, stream>>>(wq, wk, wv, wg, wo,
                                                 wt_hi, wt_lo, wot_hi, wot_lo);
    k_pairbias<<<dim3(R * R / 4), dim3(256), 0, stream>>>(z, ln_z_w, ln_z_b, w_pair, pbuf);
    k_proj<<<dim3(1536), dim3(256), 0, stream>>>(m, ln_m_w, ln_m_b,
                                                 wt_hi, wt_lo, bg, qb, kb, vtb, gbuf);
    k_attn<<<dim3(S * H), dim3(256), 0, stream>>>(qb, kb, vtb, gbuf, pbuf, mask, ogb);
    k_outproj<<<dim3(768), dim3(256), 0, stream>>>(ogb, wot_hi, wot_lo, bo, out);
}

// Round 6
// 621.577 us; speedup vs baseline: 1.0200x; 1.0119x over previous
//
#include <hip/hip_runtime.h>
#include <hip/hip_bf16.h>

#define S 128
#define R 384
#define CIN 256
#define H 8
#define D 32
#define CZ 128
#define E 256   // H*D

typedef __attribute__((ext_vector_type(8))) short short8;
typedef __attribute__((ext_vector_type(4))) short short4_;
typedef __attribute__((ext_vector_type(4))) float f32x4;
typedef __attribute__((ext_vector_type(4))) unsigned int u32x4;
typedef __attribute__((ext_vector_type(8))) _Float16 half8;

union U8 { short8 s; unsigned int u[4]; };

__device__ __forceinline__ unsigned short f2bs_u(float f) {
    __hip_bfloat16 h = __float2bfloat16(f);
    return *reinterpret_cast<unsigned short*>(&h);
}
__device__ __forceinline__ short f2bs(float f) {
    __hip_bfloat16 h = __float2bfloat16(f);
    return *reinterpret_cast<short*>(&h);
}
__device__ __forceinline__ float bs2f(unsigned short u) {
    union { unsigned int i; float f; } c;
    c.i = ((unsigned int)u) << 16;
    return c.f;
}
// fp16 bit helpers
__device__ __forceinline__ short f2hs(float f) {
    _Float16 h = (_Float16)f;
    return *reinterpret_cast<short*>(&h);
}
__device__ __forceinline__ float hs2f(unsigned short u) {
    _Float16 h = *reinterpret_cast<_Float16*>(&u);
    return (float)h;
}
// pack f32 -> (hi bf16 in low16, lo bf16 in high16)
__device__ __forceinline__ unsigned int packhl(float x) {
    unsigned short h = f2bs_u(x);
    float rem = x - bs2f(h);
    unsigned short l = f2bs_u(rem);
    return (unsigned int)h | ((unsigned int)l << 16);
}
// 4x4 transpose across 4 lanes (p = lane&3), regs x0..x3
__device__ __forceinline__ void xpose4(float& x0, float& x1, float& x2, float& x3, int p) {
    float tmp;
    if (p & 1) { tmp = x0; x0 = x1; x1 = tmp; tmp = x2; x2 = x3; x3 = tmp; }
    x1 = __shfl_xor(x1, 1); x3 = __shfl_xor(x3, 1);
    if (p & 1) { tmp = x0; x0 = x1; x1 = tmp; tmp = x2; x2 = x3; x3 = tmp; }
    if (p & 2) { tmp = x0; x0 = x2; x2 = tmp; tmp = x1; x1 = x3; x3 = tmp; }
    x2 = __shfl_xor(x2, 2); x3 = __shfl_xor(x3, 2);
    if (p & 2) { tmp = x0; x0 = x2; x2 = tmp; tmp = x1; x1 = x3; x3 = tmp; }
}

// ---------------------------------------------------------------------------
// K0: weight prep. Transpose to e-major and split into bf16 hi/lo. (round-1)
// blocks 0..255: wq/wk/wv/wg -> wt[mat][e][c]; blocks 256..319: wo -> wot[cout][e]
// ---------------------------------------------------------------------------
__global__ __launch_bounds__(256) void k_prepw(
    const float* __restrict__ wq, const float* __restrict__ wk,
    const float* __restrict__ wv, const float* __restrict__ wg,
    const float* __restrict__ wo,
    unsigned short* __restrict__ wt_hi, unsigned short* __restrict__ wt_lo,
    unsigned short* __restrict__ wot_hi, unsigned short* __restrict__ wot_lo)
{
    __shared__ float tl[32][36];
    const int b = blockIdx.x, t = threadIdx.x;
    const int iswo = (b >= 256);
    const int bb = iswo ? (b - 256) : (b & 63);
    const int te = bb >> 3, tc = bb & 7;
    const int mat = b >> 6;
    const float* src = iswo ? wo : (mat == 0 ? wq : mat == 1 ? wk : mat == 2 ? wv : wg);
    unsigned short* dh = iswo ? wot_hi : wt_hi + (size_t)mat * 65536;
    unsigned short* dl = iswo ? wot_lo : wt_lo + (size_t)mat * 65536;

    const int r = t >> 3, c4 = (t & 7) * 4;
    float4 v = *(const float4*)(src + (size_t)(tc * 32 + r) * 256 + te * 32 + c4);
    tl[r][c4] = v.x; tl[r][c4 + 1] = v.y; tl[r][c4 + 2] = v.z; tl[r][c4 + 3] = v.w;
    __syncthreads();
    short4_ hv, lv;
#pragma unroll
    for (int j = 0; j < 4; j++) {
        float x = tl[c4 + j][r];
        unsigned short hb = f2bs_u(x);
        hv[j] = (short)hb;
        lv[j] = f2bs(x - bs2f(hb));
    }
    size_t o = (size_t)(te * 32 + r) * 256 + tc * 32 + c4;
    *(short4_*)(dh + o) = hv;
    *(short4_*)(dl + o) = lv;
}

// ---------------------------------------------------------------------------
// K1: pair bias (f32, unchanged)
// ---------------------------------------------------------------------------
__global__ __launch_bounds__(256) void k_pairbias(
    const float* __restrict__ z, const float* __restrict__ lnw,
    const float* __restrict__ lnb, const float* __restrict__ wp,
    float* __restrict__ pb)
{
    int wid  = blockIdx.x * 4 + (threadIdx.x >> 6);
    int lane = threadIdx.x & 63;
    int qi = wid / R;
    int ki = wid - qi * R;
    const float* zr = z + (size_t)wid * CZ;
    float z0 = zr[lane], z1 = zr[lane + 64];
    float s  = z0 + z1;
    float sq = z0 * z0 + z1 * z1;
#pragma unroll
    for (int off = 32; off >= 1; off >>= 1) {
        s  += __shfl_xor(s, off);
        sq += __shfl_xor(sq, off);
    }
    float mu   = s * (1.0f / CZ);
    float var  = sq * (1.0f / CZ) - mu * mu;
    float rstd = rsqrtf(var + 1e-5f);
    float zl0 = (z0 - mu) * rstd * lnw[lane]      + lnb[lane];
    float zl1 = (z1 - mu) * rstd * lnw[lane + 64] + lnb[lane + 64];
    const float* w0 = wp + lane * H;
    const float* w1 = wp + (lane + 64) * H;
    float ph[H];
#pragma unroll
    for (int h = 0; h < H; h++) ph[h] = zl0 * w0[h] + zl1 * w1[h];
#pragma unroll
    for (int off = 32; off >= 1; off >>= 1) {
#pragma unroll
        for (int h = 0; h < H; h++) ph[h] += __shfl_xor(ph[h], off);
    }
    if (lane == 0) {
#pragma unroll
        for (int h = 0; h < H; h++)
            pb[((size_t)h * R + qi) * R + ki] = ph[h];
    }
}

// ---------------------------------------------------------------------------
// K2 v8: round-1 geometry (64-row tile, 4 waves, acc[4][4], LDS 68 KB ->
// 2 blocks/CU LDS-bound) + explicit ping-pong B-register prefetch.
// Lesson r4/r5: this kernel is ILP-bound; occupancy pushes starved the
// allocator (VGPR 64) and regressed. Here LB(256,2) leaves up to 256 VGPRs
// per wave; kk+1's 8 B-fragments are loaded BEFORE kk's MFMA block so L2
// latency hides under MFMA + ds_read. Numerics identical to round 1.
// ---------------------------------------------------------------------------
#define PROJ_MFMA_STEP(KK, BH, BL) do { \
    const int kcol_ = (KK) * 32 + quad * 8; \
    short8 ah_[4], al_[4]; \
    _Pragma("unroll") \
    for (int mt = 0; mt < 4; mt++) { \
        ah_[mt] = *(const short8*)&Ah[mt * 16 + ln][kcol_]; \
        al_[mt] = *(const short8*)&Al[mt * 16 + ln][kcol_]; \
    } \
    _Pragma("unroll") \
    for (int nt = 0; nt < 4; nt++) { \
        _Pragma("unroll") \
        for (int mt = 0; mt < 4; mt++) { \
            acc[mt][nt] = __builtin_amdgcn_mfma_f32_16x16x32_bf16(ah_[mt], BH[nt], acc[mt][nt], 0, 0, 0); \
            acc[mt][nt] = __builtin_amdgcn_mfma_f32_16x16x32_bf16(al_[mt], BH[nt], acc[mt][nt], 0, 0, 0); \
            acc[mt][nt] = __builtin_amdgcn_mfma_f32_16x16x32_bf16(ah_[mt], BL[nt], acc[mt][nt], 0, 0, 0); \
        } \
    } \
} while (0)

__global__ __launch_bounds__(256, 2) void k_proj(
    const float* __restrict__ m, const float* __restrict__ lnw,
    const float* __restrict__ lnb,
    const unsigned short* __restrict__ wt_hi, const unsigned short* __restrict__ wt_lo,
    const float* __restrict__ bg,
    unsigned short* __restrict__ qb, unsigned short* __restrict__ kb,
    unsigned short* __restrict__ vtb, unsigned short* __restrict__ gb)
{
    __shared__ unsigned short Ah[64][264];
    __shared__ unsigned short Al[64][264];
    __shared__ float muv[64][2];
    const int t = threadIdx.x;
    const int row0 = blockIdx.x * 64;
    const int sblk = blockIdx.x / 6;
    const int res0 = (blockIdx.x % 6) * 64;

    // pass 1: LN stats, 2 threads per row (partners adjacent in wave)
    if (t < 128) {
        int r = t >> 1, half = t & 1;
        const float* mr = m + (size_t)(row0 + r) * CIN + half * 128;
        float s = 0.f, sq = 0.f;
#pragma unroll
        for (int i = 0; i < 32; i++) {
            f32x4 v = *(const f32x4*)(mr + i * 4);
#pragma unroll
            for (int q = 0; q < 4; q++) { s += v[q]; sq += v[q] * v[q]; }
        }
        s  += __shfl_xor(s, 1);
        sq += __shfl_xor(sq, 1);
        if (half == 0) {
            float mu  = s * (1.0f / CIN);
            float var = sq * (1.0f / CIN) - mu * mu;
            muv[r][0] = mu;
            muv[r][1] = rsqrtf(var + 1e-5f);
        }
    }
    __syncthreads();
    // pass 2: normalize + bf16 hi/lo -> LDS planes
#pragma unroll
    for (int i = 0; i < 16; i++) {
        int idx = i * 256 + t;
        int r = idx >> 6, c4 = (idx & 63) * 4;
        f32x4 v = *(const f32x4*)(m + (size_t)(row0 + r) * CIN + c4);
        float4 lw = *(const float4*)(lnw + c4);
        float4 lb = *(const float4*)(lnb + c4);
        float mu = muv[r][0], rs = muv[r][1];
        short4_ oh, ol;
#pragma unroll
        for (int j = 0; j < 4; j++) {
            float lwj = (j == 0) ? lw.x : (j == 1) ? lw.y : (j == 2) ? lw.z : lw.w;
            float lbj = (j == 0) ? lb.x : (j == 1) ? lb.y : (j == 2) ? lb.z : lb.w;
            float x = (v[j] - mu) * rs * lwj + lbj;
            unsigned short hb = f2bs_u(x);
            oh[j] = (short)hb;
            ol[j] = f2bs(x - bs2f(hb));
        }
        *(short4_*)&Ah[r][c4] = oh;
        *(short4_*)&Al[r][c4] = ol;
    }
    __syncthreads();

    const int w = t >> 6, lane = t & 63, ln = lane & 15, quad = lane >> 4;
    const unsigned short* Bh = wt_hi + (size_t)w * 65536;
    const unsigned short* Bl = wt_lo + (size_t)w * 65536;

    for (int nc = 0; nc < 4; nc++) {
        const int nbase = nc * 64;
        f32x4 acc[4][4];
#pragma unroll
        for (int a = 0; a < 4; a++)
#pragma unroll
            for (int b = 0; b < 4; b++) acc[a][b] = (f32x4){0.f, 0.f, 0.f, 0.f};

        // per-nt row pointers (include quad's k-offset)
        const unsigned short* bhp[4];
        const unsigned short* blp[4];
#pragma unroll
        for (int nt = 0; nt < 4; nt++) {
            size_t rb = (size_t)(nbase + nt * 16 + ln) * 256 + quad * 8;
            bhp[nt] = Bh + rb;
            blp[nt] = Bl + rb;
        }

        // ping-pong B prefetch: load kk+1 before MFMAs of kk
        short8 bhA[4], blA[4], bhB[4], blB[4];
#pragma unroll
        for (int nt = 0; nt < 4; nt++) {
            bhA[nt] = *(const short8*)(bhp[nt]);
            blA[nt] = *(const short8*)(blp[nt]);
        }
#pragma unroll
        for (int kp = 0; kp < 4; kp++) {
            const int k0 = kp * 2;
#pragma unroll
            for (int nt = 0; nt < 4; nt++) {
                bhB[nt] = *(const short8*)(bhp[nt] + (k0 + 1) * 32);
                blB[nt] = *(const short8*)(blp[nt] + (k0 + 1) * 32);
            }
            PROJ_MFMA_STEP(k0, bhA, blA);
            if (kp < 3) {
#pragma unroll
                for (int nt = 0; nt < 4; nt++) {
                    bhA[nt] = *(const short8*)(bhp[nt] + (k0 + 2) * 32);
                    blA[nt] = *(const short8*)(blp[nt] + (k0 + 2) * 32);
                }
            }
            PROJ_MFMA_STEP(k0 + 1, bhB, blB);
        }

        // epilogue (outputs fp16) — identical to round 1
        if (w == 2) {
            // V: C-layout is res-contiguous per lane -> vt[h][d][res]
#pragma unroll
            for (int mt = 0; mt < 4; mt++) {
                int resg = res0 + mt * 16 + quad * 4;
#pragma unroll
                for (int nt = 0; nt < 4; nt++) {
                    int e = nbase + nt * 16 + ln;
                    int hh = e >> 5, d = e & 31;
                    f32x4 a = acc[mt][nt];
                    short4_ vv;
                    vv[0] = f2hs(a[0]); vv[1] = f2hs(a[1]);
                    vv[2] = f2hs(a[2]); vv[3] = f2hs(a[3]);
                    *(short4_*)(vtb + (((size_t)(sblk * H + hh)) * D + d) * R + resg) = vv;
                }
            }
        } else if (w == 3) {
            const int p = ln & 3;
#pragma unroll
            for (int mt = 0; mt < 4; mt++) {
                int rowg = row0 + mt * 16 + quad * 4 + p;
#pragma unroll
                for (int nt = 0; nt < 4; nt++) {
                    int e0 = nbase + nt * 16 + (ln & 12);
                    f32x4 a = acc[mt][nt];
                    float x0 = a[0], x1 = a[1], x2 = a[2], x3 = a[3];
                    xpose4(x0, x1, x2, x3, p);
                    float4 bgv = *(const float4*)(bg + e0);
                    short4_ gv;
                    gv[0] = f2hs(1.0f / (1.0f + __expf(-(x0 + bgv.x))));
                    gv[1] = f2hs(1.0f / (1.0f + __expf(-(x1 + bgv.y))));
                    gv[2] = f2hs(1.0f / (1.0f + __expf(-(x2 + bgv.z))));
                    gv[3] = f2hs(1.0f / (1.0f + __expf(-(x3 + bgv.w))));
                    *(short4_*)(gb + (size_t)rowg * E + e0) = gv;
                }
            }
        } else {
            const float sc = (w == 0) ? 0.17677669529663687f : 1.0f;
            unsigned short* dst = (w == 0) ? qb : kb;
            const int p = ln & 3;
#pragma unroll
            for (int mt = 0; mt < 4; mt++) {
                int resg = res0 + mt * 16 + quad * 4 + p;
#pragma unroll
                for (int nt = 0; nt < 4; nt++) {
                    int e0 = nbase + nt * 16 + (ln & 12);
                    f32x4 a = acc[mt][nt];
                    float x0 = a[0] * sc, x1 = a[1] * sc, x2 = a[2] * sc, x3 = a[3] * sc;
                    xpose4(x0, x1, x2, x3, p);
                    int hh = e0 >> 5, d0 = e0 & 31;
                    short4_ vv;
                    vv[0] = f2hs(x0); vv[1] = f2hs(x1); vv[2] = f2hs(x2); vv[3] = f2hs(x3);
                    *(short4_*)(dst + (((size_t)(sblk * H + hh)) * R + resg) * D + d0) = vv;
                }
            }
        }
    }
}

// ---------------------------------------------------------------------------
// K3: MFMA attention — fp16 operands (q/k/v/P/g), f32 accum, f32 bias.
// Unchanged (verified passing).
// ---------------------------------------------------------------------------
__global__ __launch_bounds__(256, 2) void k_attn(
    const unsigned short* __restrict__ qb, const unsigned short* __restrict__ kb,
    const unsigned short* __restrict__ vtb, const unsigned short* __restrict__ gb,
    const float* __restrict__ pb, const float* __restrict__ mask,
    float* __restrict__ og)
{
    __shared__ unsigned short Ks[R][40];
    __shared__ unsigned short Vt[D][392];
    __shared__ float Ps[4][16][100];
    const int t = threadIdx.x;
    const int s = blockIdx.x >> 3;
    const int h = blockIdx.x & 7;
    const size_t kvbase = (size_t)(s * H + h) * R * D;

#pragma unroll
    for (int i = 0; i < 6; i++) {
        int idx = i * 256 + t;
        int res = idx >> 2, d = (idx & 3) * 8;
        *(short8*)&Ks[res][d] = *(const short8*)(kb + kvbase + (size_t)res * D + d);
    }
#pragma unroll
    for (int i = 0; i < 6; i++) {
        int idx = i * 256 + t;
        int d = idx / 48, j = idx - d * 48;
        *(short8*)&Vt[d][j * 8] = *(const short8*)(vtb + kvbase + (size_t)d * R + j * 8);
    }
    __syncthreads();

    const int w = t >> 6;
    const int lane = t & 63;
    const int ln = lane & 15;
    const int quad = lane >> 4;
    float (*Pw)[100] = Ps[w];

    float mr[24];
#pragma unroll
    for (int tt = 0; tt < 24; tt++)
        mr[tt] = 1e9f * (mask[s * R + tt * 16 + ln] - 1.0f);

    for (int qt = 0; qt < 6; qt++) {
        const int q0 = w * 96 + qt * 16;
        half8 aq = *(const half8*)(qb + kvbase + (size_t)(q0 + ln) * D + quad * 8);
        const float* pbrow = pb + ((size_t)h * R + q0 + quad * 4) * R + ln;

        f32x4 acc[24];
#pragma unroll
        for (int tt = 0; tt < 24; tt++) {
            f32x4 c;
#pragma unroll
            for (int r = 0; r < 4; r++)
                c[r] = pbrow[(size_t)r * R + tt * 16] + mr[tt];
            half8 bk = *(const half8*)&Ks[tt * 16 + ln][quad * 8];
            acc[tt] = __builtin_amdgcn_mfma_f32_16x16x32_f16(aq, bk, c, 0, 0, 0);
        }
        float l[4];
#pragma unroll
        for (int r = 0; r < 4; r++) {
            float mx = acc[0][r];
#pragma unroll
            for (int tt = 1; tt < 24; tt++) mx = fmaxf(mx, acc[tt][r]);
            mx = fmaxf(mx, __shfl_xor(mx, 1));
            mx = fmaxf(mx, __shfl_xor(mx, 2));
            mx = fmaxf(mx, __shfl_xor(mx, 4));
            mx = fmaxf(mx, __shfl_xor(mx, 8));
            float sum = 0.f;
#pragma unroll
            for (int tt = 0; tt < 24; tt++) {
                float p = __expf(acc[tt][r] - mx);
                acc[tt][r] = p;
                sum += p;
            }
            sum += __shfl_xor(sum, 1);
            sum += __shfl_xor(sum, 2);
            sum += __shfl_xor(sum, 4);
            sum += __shfl_xor(sum, 8);
            l[r] = sum;
        }
        f32x4 o0 = {0.f, 0.f, 0.f, 0.f}, o1 = {0.f, 0.f, 0.f, 0.f};
        for (int cc = 0; cc < 4; cc++) {
#pragma unroll
            for (int tt6 = 0; tt6 < 6; tt6++) {
                int tt = cc * 6 + tt6;
#pragma unroll
                for (int r = 0; r < 4; r++)
                    Pw[quad * 4 + r][tt6 * 16 + ln] = acc[tt][r];
            }
#pragma unroll
            for (int kk = 0; kk < 3; kk++) {
                f32x4 plo = *(f32x4*)&Pw[ln][kk * 32 + quad * 8];
                f32x4 phi = *(f32x4*)&Pw[ln][kk * 32 + quad * 8 + 4];
                half8 ap;
#pragma unroll
                for (int j = 0; j < 4; j++) {
                    ap[j]     = (_Float16)plo[j];
                    ap[4 + j] = (_Float16)phi[j];
                }
                int kg = cc * 96 + kk * 32;
                half8 bv0 = *(const half8*)&Vt[ln][kg + quad * 8];
                half8 bv1 = *(const half8*)&Vt[16 + ln][kg + quad * 8];
                o0 = __builtin_amdgcn_mfma_f32_16x16x32_f16(ap, bv0, o0, 0, 0, 0);
                o1 = __builtin_amdgcn_mfma_f32_16x16x32_f16(ap, bv1, o1, 0, 0, 0);
            }
        }
#pragma unroll
        for (int r = 0; r < 4; r++) {
            int mrow = quad * 4 + r;
            int rw = s * R + q0 + mrow;
            float invl = 1.0f / l[r];
            size_t base = (size_t)rw * E + h * D;
            float g0 = hs2f(gb[base + ln]);
            float g1 = hs2f(gb[base + 16 + ln]);
            og[base + ln]      = o0[r] * invl * g0;
            og[base + 16 + ln] = o1[r] * invl * g1;
        }
    }
}

// ---------------------------------------------------------------------------
// K4: out = og @ wo + bo via split-bf16 MFMA (round-1, verified)
// ---------------------------------------------------------------------------
__global__ __launch_bounds__(256, 2) void k_outproj(
    const float* __restrict__ og, const unsigned short* __restrict__ wot_hi,
    const unsigned short* __restrict__ wot_lo, const float* __restrict__ bo,
    float* __restrict__ out)
{
    __shared__ unsigned int otb[64][260];
    const int t = threadIdx.x;
    const int row0 = blockIdx.x * 64;
#pragma unroll
    for (int i = 0; i < 16; i++) {
        int e4 = i * 256 + t;
        int r = e4 >> 6, c = (e4 & 63) * 4;
        f32x4 v = *(const f32x4*)(og + (size_t)(row0 + r) * E + c);
        u32x4 pk;
        pk[0] = packhl(v[0]); pk[1] = packhl(v[1]);
        pk[2] = packhl(v[2]); pk[3] = packhl(v[3]);
        *(u32x4*)&otb[r][c] = pk;
    }
    __syncthreads();

    const int w = t >> 6, lane = t & 63, ln = lane & 15, quad = lane >> 4;
    const int nbase = w * 64;
    f32x4 acc[4][4];
#pragma unroll
    for (int a = 0; a < 4; a++)
#pragma unroll
        for (int b = 0; b < 4; b++) acc[a][b] = (f32x4){0.f, 0.f, 0.f, 0.f};

    for (int kk = 0; kk < 8; kk++) {
        const int kcol = kk * 32 + quad * 8;
        short8 ah[4], al[4];
#pragma unroll
        for (int mt = 0; mt < 4; mt++) {
            const unsigned int* up = &otb[mt * 16 + ln][kcol];
            u32x4 u0 = *(const u32x4*)up;
            u32x4 u1 = *(const u32x4*)(up + 4);
            U8 A, L;
            A.u[0] = (u0[0] & 0xffffu) | (u0[1] << 16);
            A.u[1] = (u0[2] & 0xffffu) | (u0[3] << 16);
            A.u[2] = (u1[0] & 0xffffu) | (u1[1] << 16);
            A.u[3] = (u1[2] & 0xffffu) | (u1[3] << 16);
            L.u[0] = (u0[0] >> 16) | (u0[1] & 0xffff0000u);
            L.u[1] = (u0[2] >> 16) | (u0[3] & 0xffff0000u);
            L.u[2] = (u1[0] >> 16) | (u1[1] & 0xffff0000u);
            L.u[3] = (u1[2] >> 16) | (u1[3] & 0xffff0000u);
            ah[mt] = A.s; al[mt] = L.s;
        }
#pragma unroll
        for (int nt = 0; nt < 4; nt++) {
            size_t boff = (size_t)(nbase + nt * 16 + ln) * 256 + kcol;
            short8 bh = *(const short8*)(wot_hi + boff);
            short8 bl = *(const short8*)(wot_lo + boff);
#pragma unroll
            for (int mt = 0; mt < 4; mt++) {
                acc[mt][nt] = __builtin_amdgcn_mfma_f32_16x16x32_bf16(ah[mt], bh, acc[mt][nt], 0, 0, 0);
                acc[mt][nt] = __builtin_amdgcn_mfma_f32_16x16x32_bf16(al[mt], bh, acc[mt][nt], 0, 0, 0);
                acc[mt][nt] = __builtin_amdgcn_mfma_f32_16x16x32_bf16(ah[mt], bl, acc[mt][nt], 0, 0, 0);
            }
        }
    }
    const int p = ln & 3;
#pragma unroll
    for (int mt = 0; mt < 4; mt++) {
        int rowg = row0 + mt * 16 + quad * 4 + p;
#pragma unroll
        for (int nt = 0; nt < 4; nt++) {
            int c0 = nbase + nt * 16 + (ln & 12);
            f32x4 a = acc[mt][nt];
            float x0 = a[0], x1 = a[1], x2 = a[2], x3 = a[3];
            xpose4(x0, x1, x2, x3, p);
            float4 bov = *(const float4*)(bo + c0);
            f32x4 o;
            o[0] = x0 + bov.x; o[1] = x1 + bov.y;
            o[2] = x2 + bov.z; o[3] = x3 + bov.w;
            *(f32x4*)(out + (size_t)rowg * CIN + c0) = o;
        }
    }
}

// ---------------------------------------------------------------------------
extern "C" void kernel_launch(void* const* d_in, const int* in_sizes, int n_in,
                              void* d_out, int out_size, void* d_ws, size_t ws_size,
                              hipStream_t stream)
{
    const float* m      = (const float*)d_in[0];
    const float* z      = (const float*)d_in[1];
    const float* mask   = (const float*)d_in[2];
    const float* ln_m_w = (const float*)d_in[3];
    const float* ln_m_b = (const float*)d_in[4];
    const float* ln_z_w = (const float*)d_in[5];
    const float* ln_z_b = (const float*)d_in[6];
    const float* w_pair = (const float*)d_in[7];
    const float* wq     = (const float*)d_in[8];
    const float* wk     = (const float*)d_in[9];
    const float* wv     = (const float*)d_in[10];
    const float* wg     = (const float*)d_in[11];
    const float* bg     = (const float*)d_in[12];
    const float* wo     = (const float*)d_in[13];
    const float* bo     = (const float*)d_in[14];
    float* out = (float*)d_out;

    char* ws = (char*)d_ws;
    float*          pbuf   = (float*)ws;              ws += 4718592;
    unsigned short* qb     = (unsigned short*)ws;     ws += 25165824;
    unsigned short* kb     = (unsigned short*)ws;     ws += 25165824;
    unsigned short* vtb    = (unsigned short*)ws;     ws += 25165824;
    unsigned short* gbuf   = (unsigned short*)ws;     ws += 25165824;
    float*          ogb    = (float*)ws;              ws += 50331648;
    unsigned short* wt_hi  = (unsigned short*)ws;     ws += 524288;
    unsigned short* wt_lo  = (unsigned short*)ws;     ws += 524288;
    unsigned short* wot_hi = (unsigned short*)ws;     ws += 131072;
    unsigned short* wot_lo = (unsigned short*)ws;     ws += 131072;

    k_prepw<<<dim3(320), dim3(256), 0, stream>>>(wq, wk, wv, wg, wo,
                                                 wt_hi, wt_lo, wot_hi, wot_lo);
    k_pairbias<<<dim3(R * R / 4), dim3(256), 0, stream>>>(z, ln_z_w, ln_z_b, w_pair, pbuf);
    k_proj<<<dim3(768), dim3(256), 0, stream>>>(m, ln_m_w, ln_m_b,
                                                wt_hi, wt_lo, bg, qb, kb, vtb, gbuf);
    k_attn<<<dim3(S * H), dim3(256), 0, stream>>>(qb, kb, vtb, gbuf, pbuf, mask, ogb);
    k_outproj<<<dim3(768), dim3(256), 0, stream>>>(ogb, wot_hi, wot_lo, bo, out);
}

// Round 8
// 530.984 us; speedup vs baseline: 1.1941x; 1.1706x over previous
//
#include <hip/hip_runtime.h>
#include <hip/hip_bf16.h>

#define S 128
#define R 384
#define CIN 256
#define H 8
#define D 32
#define CZ 128
#define E 256   // H*D

typedef __attribute__((ext_vector_type(8))) short short8;
typedef __attribute__((ext_vector_type(4))) short short4_;
typedef __attribute__((ext_vector_type(4))) float f32x4;
typedef __attribute__((ext_vector_type(4))) unsigned int u32x4;
typedef __attribute__((ext_vector_type(8))) _Float16 half8;

union U8 { short8 s; unsigned int u[4]; };

__device__ __forceinline__ unsigned short f2bs_u(float f) {
    __hip_bfloat16 h = __float2bfloat16(f);
    return *reinterpret_cast<unsigned short*>(&h);
}
__device__ __forceinline__ short f2bs(float f) {
    __hip_bfloat16 h = __float2bfloat16(f);
    return *reinterpret_cast<short*>(&h);
}
__device__ __forceinline__ float bs2f(unsigned short u) {
    union { unsigned int i; float f; } c;
    c.i = ((unsigned int)u) << 16;
    return c.f;
}
// fp16 bit helpers
__device__ __forceinline__ short f2hs(float f) {
    _Float16 h = (_Float16)f;
    return *reinterpret_cast<short*>(&h);
}
__device__ __forceinline__ float hs2f(unsigned short u) {
    _Float16 h = *reinterpret_cast<_Float16*>(&u);
    return (float)h;
}
// pack f32 -> (hi bf16 in low16, lo bf16 in high16)
__device__ __forceinline__ unsigned int packhl(float x) {
    unsigned short h = f2bs_u(x);
    float rem = x - bs2f(h);
    unsigned short l = f2bs_u(rem);
    return (unsigned int)h | ((unsigned int)l << 16);
}
// 4x4 transpose across 4 lanes (p = lane&3), regs x0..x3
__device__ __forceinline__ void xpose4(float& x0, float& x1, float& x2, float& x3, int p) {
    float tmp;
    if (p & 1) { tmp = x0; x0 = x1; x1 = tmp; tmp = x2; x2 = x3; x3 = tmp; }
    x1 = __shfl_xor(x1, 1); x3 = __shfl_xor(x3, 1);
    if (p & 1) { tmp = x0; x0 = x1; x1 = tmp; tmp = x2; x2 = x3; x3 = tmp; }
    if (p & 2) { tmp = x0; x0 = x2; x2 = tmp; tmp = x1; x1 = x3; x3 = tmp; }
    x2 = __shfl_xor(x2, 2); x3 = __shfl_xor(x3, 2);
    if (p & 2) { tmp = x0; x0 = x2; x2 = tmp; tmp = x1; x1 = x3; x3 = tmp; }
}

// ---------------------------------------------------------------------------
// K0: weight prep. Transpose to e-major and split into bf16 hi/lo. (round-1)
// blocks 0..255: wq/wk/wv/wg -> wt[mat][e][c]; blocks 256..319: wo -> wot[cout][e]
// ---------------------------------------------------------------------------
__global__ __launch_bounds__(256) void k_prepw(
    const float* __restrict__ wq, const float* __restrict__ wk,
    const float* __restrict__ wv, const float* __restrict__ wg,
    const float* __restrict__ wo,
    unsigned short* __restrict__ wt_hi, unsigned short* __restrict__ wt_lo,
    unsigned short* __restrict__ wot_hi, unsigned short* __restrict__ wot_lo)
{
    __shared__ float tl[32][36];
    const int b = blockIdx.x, t = threadIdx.x;
    const int iswo = (b >= 256);
    const int bb = iswo ? (b - 256) : (b & 63);
    const int te = bb >> 3, tc = bb & 7;
    const int mat = b >> 6;
    const float* src = iswo ? wo : (mat == 0 ? wq : mat == 1 ? wk : mat == 2 ? wv : wg);
    unsigned short* dh = iswo ? wot_hi : wt_hi + (size_t)mat * 65536;
    unsigned short* dl = iswo ? wot_lo : wt_lo + (size_t)mat * 65536;

    const int r = t >> 3, c4 = (t & 7) * 4;
    float4 v = *(const float4*)(src + (size_t)(tc * 32 + r) * 256 + te * 32 + c4);
    tl[r][c4] = v.x; tl[r][c4 + 1] = v.y; tl[r][c4 + 2] = v.z; tl[r][c4 + 3] = v.w;
    __syncthreads();
    short4_ hv, lv;
#pragma unroll
    for (int j = 0; j < 4; j++) {
        float x = tl[c4 + j][r];
        unsigned short hb = f2bs_u(x);
        hv[j] = (short)hb;
        lv[j] = f2bs(x - bs2f(hb));
    }
    size_t o = (size_t)(te * 32 + r) * 256 + tc * 32 + c4;
    *(short4_*)(dh + o) = hv;
    *(short4_*)(dl + o) = lv;
}

// ---------------------------------------------------------------------------
// K1: pair bias (f32, unchanged)
// ---------------------------------------------------------------------------
__global__ __launch_bounds__(256) void k_pairbias(
    const float* __restrict__ z, const float* __restrict__ lnw,
    const float* __restrict__ lnb, const float* __restrict__ wp,
    float* __restrict__ pb)
{
    int wid  = blockIdx.x * 4 + (threadIdx.x >> 6);
    int lane = threadIdx.x & 63;
    int qi = wid / R;
    int ki = wid - qi * R;
    const float* zr = z + (size_t)wid * CZ;
    float z0 = zr[lane], z1 = zr[lane + 64];
    float s  = z0 + z1;
    float sq = z0 * z0 + z1 * z1;
#pragma unroll
    for (int off = 32; off >= 1; off >>= 1) {
        s  += __shfl_xor(s, off);
        sq += __shfl_xor(sq, off);
    }
    float mu   = s * (1.0f / CZ);
    float var  = sq * (1.0f / CZ) - mu * mu;
    float rstd = rsqrtf(var + 1e-5f);
    float zl0 = (z0 - mu) * rstd * lnw[lane]      + lnb[lane];
    float zl1 = (z1 - mu) * rstd * lnw[lane + 64] + lnb[lane + 64];
    const float* w0 = wp + lane * H;
    const float* w1 = wp + (lane + 64) * H;
    float ph[H];
#pragma unroll
    for (int h = 0; h < H; h++) ph[h] = zl0 * w0[h] + zl1 * w1[h];
#pragma unroll
    for (int off = 32; off >= 1; off >>= 1) {
#pragma unroll
        for (int h = 0; h < H; h++) ph[h] += __shfl_xor(ph[h], off);
    }
    if (lane == 0) {
#pragma unroll
        for (int h = 0; h < H; h++)
            pb[((size_t)h * R + qi) * R + ki] = ph[h];
    }
}

// ---------------------------------------------------------------------------
// K2: EXACT round-1 k_proj (measured 181 us, VGPR 108, no spill).
// A = bf16 hi/lo planes in LDS, B = bf16 hi/lo from global, 3 MFMAs/tile,
// fp16 output stores. LB(256,2), 64-row tile, LDS 66.5 KB -> 2 blocks/CU.
// Lesson r4/r5/r6: every schedule/occupancy intervention (512t, 32-row,
// manual ping-pong) perturbed register allocation and regressed 1.5-1.7x.
// Do not touch this kernel's structure.
// ---------------------------------------------------------------------------
__global__ __launch_bounds__(256, 2) void k_proj(
    const float* __restrict__ m, const float* __restrict__ lnw,
    const float* __restrict__ lnb,
    const unsigned short* __restrict__ wt_hi, const unsigned short* __restrict__ wt_lo,
    const float* __restrict__ bg,
    unsigned short* __restrict__ qb, unsigned short* __restrict__ kb,
    unsigned short* __restrict__ vtb, unsigned short* __restrict__ gb)
{
    __shared__ unsigned short Ah[64][264];
    __shared__ unsigned short Al[64][264];
    __shared__ float muv[64][2];
    const int t = threadIdx.x;
    const int row0 = blockIdx.x * 64;
    const int sblk = blockIdx.x / 6;
    const int res0 = (blockIdx.x % 6) * 64;

    // pass 1: LN stats, 2 threads per row (partners adjacent in wave)
    if (t < 128) {
        int r = t >> 1, half = t & 1;
        const float* mr = m + (size_t)(row0 + r) * CIN + half * 128;
        float s = 0.f, sq = 0.f;
#pragma unroll
        for (int i = 0; i < 32; i++) {
            f32x4 v = *(const f32x4*)(mr + i * 4);
#pragma unroll
            for (int q = 0; q < 4; q++) { s += v[q]; sq += v[q] * v[q]; }
        }
        s  += __shfl_xor(s, 1);
        sq += __shfl_xor(sq, 1);
        if (half == 0) {
            float mu  = s * (1.0f / CIN);
            float var = sq * (1.0f / CIN) - mu * mu;
            muv[r][0] = mu;
            muv[r][1] = rsqrtf(var + 1e-5f);
        }
    }
    __syncthreads();
    // pass 2: normalize + bf16 hi/lo -> LDS planes (tile is L2-hot from pass 1)
#pragma unroll
    for (int i = 0; i < 16; i++) {
        int idx = i * 256 + t;
        int r = idx >> 6, c4 = (idx & 63) * 4;
        f32x4 v = *(const f32x4*)(m + (size_t)(row0 + r) * CIN + c4);
        float4 lw = *(const float4*)(lnw + c4);
        float4 lb = *(const float4*)(lnb + c4);
        float mu = muv[r][0], rs = muv[r][1];
        short4_ oh, ol;
#pragma unroll
        for (int j = 0; j < 4; j++) {
            float lwj = (j == 0) ? lw.x : (j == 1) ? lw.y : (j == 2) ? lw.z : lw.w;
            float lbj = (j == 0) ? lb.x : (j == 1) ? lb.y : (j == 2) ? lb.z : lb.w;
            float x = (v[j] - mu) * rs * lwj + lbj;
            unsigned short hb = f2bs_u(x);
            oh[j] = (short)hb;
            ol[j] = f2bs(x - bs2f(hb));
        }
        *(short4_*)&Ah[r][c4] = oh;
        *(short4_*)&Al[r][c4] = ol;
    }
    __syncthreads();

    const int w = t >> 6, lane = t & 63, ln = lane & 15, quad = lane >> 4;
    const unsigned short* Bh = wt_hi + (size_t)w * 65536;
    const unsigned short* Bl = wt_lo + (size_t)w * 65536;

    for (int nc = 0; nc < 4; nc++) {
        const int nbase = nc * 64;
        f32x4 acc[4][4];
#pragma unroll
        for (int a = 0; a < 4; a++)
#pragma unroll
            for (int b = 0; b < 4; b++) acc[a][b] = (f32x4){0.f, 0.f, 0.f, 0.f};

#pragma unroll 2
        for (int kk = 0; kk < 8; kk++) {
            const int kcol = kk * 32 + quad * 8;
            short8 ah[4], al[4];
#pragma unroll
            for (int mt = 0; mt < 4; mt++) {
                ah[mt] = *(const short8*)&Ah[mt * 16 + ln][kcol];
                al[mt] = *(const short8*)&Al[mt * 16 + ln][kcol];
            }
#pragma unroll
            for (int nt = 0; nt < 4; nt++) {
                size_t boff = (size_t)(nbase + nt * 16 + ln) * 256 + kcol;
                short8 bh = *(const short8*)(Bh + boff);
                short8 bl = *(const short8*)(Bl + boff);
#pragma unroll
                for (int mt = 0; mt < 4; mt++) {
                    acc[mt][nt] = __builtin_amdgcn_mfma_f32_16x16x32_bf16(ah[mt], bh, acc[mt][nt], 0, 0, 0);
                    acc[mt][nt] = __builtin_amdgcn_mfma_f32_16x16x32_bf16(al[mt], bh, acc[mt][nt], 0, 0, 0);
                    acc[mt][nt] = __builtin_amdgcn_mfma_f32_16x16x32_bf16(ah[mt], bl, acc[mt][nt], 0, 0, 0);
                }
            }
        }
        // epilogue (all outputs fp16)
        if (w == 2) {
            // V: C-layout is res-contiguous per lane -> vt[h][d][res]
#pragma unroll
            for (int mt = 0; mt < 4; mt++) {
                int resg = res0 + mt * 16 + quad * 4;
#pragma unroll
                for (int nt = 0; nt < 4; nt++) {
                    int e = nbase + nt * 16 + ln;
                    int hh = e >> 5, d = e & 31;
                    f32x4 a = acc[mt][nt];
                    short4_ vv;
                    vv[0] = f2hs(a[0]); vv[1] = f2hs(a[1]);
                    vv[2] = f2hs(a[2]); vv[3] = f2hs(a[3]);
                    *(short4_*)(vtb + (((size_t)(sblk * H + hh)) * D + d) * R + resg) = vv;
                }
            }
        } else if (w == 3) {
            const int p = ln & 3;
#pragma unroll
            for (int mt = 0; mt < 4; mt++) {
                int rowg = row0 + mt * 16 + quad * 4 + p;
#pragma unroll
                for (int nt = 0; nt < 4; nt++) {
                    int e0 = nbase + nt * 16 + (ln & 12);
                    f32x4 a = acc[mt][nt];
                    float x0 = a[0], x1 = a[1], x2 = a[2], x3 = a[3];
                    xpose4(x0, x1, x2, x3, p);
                    float4 bgv = *(const float4*)(bg + e0);
                    short4_ gv;
                    gv[0] = f2hs(1.0f / (1.0f + __expf(-(x0 + bgv.x))));
                    gv[1] = f2hs(1.0f / (1.0f + __expf(-(x1 + bgv.y))));
                    gv[2] = f2hs(1.0f / (1.0f + __expf(-(x2 + bgv.z))));
                    gv[3] = f2hs(1.0f / (1.0f + __expf(-(x3 + bgv.w))));
                    *(short4_*)(gb + (size_t)rowg * E + e0) = gv;
                }
            }
        } else {
            const float sc = (w == 0) ? 0.17677669529663687f : 1.0f;
            unsigned short* dst = (w == 0) ? qb : kb;
            const int p = ln & 3;
#pragma unroll
            for (int mt = 0; mt < 4; mt++) {
                int resg = res0 + mt * 16 + quad * 4 + p;
#pragma unroll
                for (int nt = 0; nt < 4; nt++) {
                    int e0 = nbase + nt * 16 + (ln & 12);
                    f32x4 a = acc[mt][nt];
                    float x0 = a[0] * sc, x1 = a[1] * sc, x2 = a[2] * sc, x3 = a[3] * sc;
                    xpose4(x0, x1, x2, x3, p);
                    int hh = e0 >> 5, d0 = e0 & 31;
                    short4_ vv;
                    vv[0] = f2hs(x0); vv[1] = f2hs(x1); vv[2] = f2hs(x2); vv[3] = f2hs(x3);
                    *(short4_*)(dst + (((size_t)(sblk * H + hh)) * R + resg) * D + d0) = vv;
                }
            }
        }
    }
}

// ---------------------------------------------------------------------------
// K3: MFMA attention — fp16 operands. P now stored in LDS as fp16 (the
// conversion to fp16 happened anyway before the PV MFMA — moving it before
// the LDS store is value-identical). LDS 81.4 -> 69.1 KB => 2 blocks/CU
// (was 1), doubling occupancy. Everything else unchanged.
// ---------------------------------------------------------------------------
__global__ __launch_bounds__(256, 2) void k_attn(
    const unsigned short* __restrict__ qb, const unsigned short* __restrict__ kb,
    const unsigned short* __restrict__ vtb, const unsigned short* __restrict__ gb,
    const float* __restrict__ pb, const float* __restrict__ mask,
    float* __restrict__ og)
{
    __shared__ unsigned short Ks[R][40];
    __shared__ unsigned short Vt[D][392];
    __shared__ unsigned short Ps[4][16][104];   // fp16 P, 96 used + 8 pad
    const int t = threadIdx.x;
    const int s = blockIdx.x >> 3;
    const int h = blockIdx.x & 7;
    const size_t kvbase = (size_t)(s * H + h) * R * D;

#pragma unroll
    for (int i = 0; i < 6; i++) {
        int idx = i * 256 + t;
        int res = idx >> 2, d = (idx & 3) * 8;
        *(short8*)&Ks[res][d] = *(const short8*)(kb + kvbase + (size_t)res * D + d);
    }
#pragma unroll
    for (int i = 0; i < 6; i++) {
        int idx = i * 256 + t;
        int d = idx / 48, j = idx - d * 48;
        *(short8*)&Vt[d][j * 8] = *(const short8*)(vtb + kvbase + (size_t)d * R + j * 8);
    }
    __syncthreads();

    const int w = t >> 6;
    const int lane = t & 63;
    const int ln = lane & 15;
    const int quad = lane >> 4;
    unsigned short (*Pw)[104] = Ps[w];

    float mr[24];
#pragma unroll
    for (int tt = 0; tt < 24; tt++)
        mr[tt] = 1e9f * (mask[s * R + tt * 16 + ln] - 1.0f);

    for (int qt = 0; qt < 6; qt++) {
        const int q0 = w * 96 + qt * 16;
        half8 aq = *(const half8*)(qb + kvbase + (size_t)(q0 + ln) * D + quad * 8);
        const float* pbrow = pb + ((size_t)h * R + q0 + quad * 4) * R + ln;

        f32x4 acc[24];
#pragma unroll
        for (int tt = 0; tt < 24; tt++) {
            f32x4 c;
#pragma unroll
            for (int r = 0; r < 4; r++)
                c[r] = pbrow[(size_t)r * R + tt * 16] + mr[tt];
            half8 bk = *(const half8*)&Ks[tt * 16 + ln][quad * 8];
            acc[tt] = __builtin_amdgcn_mfma_f32_16x16x32_f16(aq, bk, c, 0, 0, 0);
        }
        float l[4];
#pragma unroll
        for (int r = 0; r < 4; r++) {
            float mx = acc[0][r];
#pragma unroll
            for (int tt = 1; tt < 24; tt++) mx = fmaxf(mx, acc[tt][r]);
            mx = fmaxf(mx, __shfl_xor(mx, 1));
            mx = fmaxf(mx, __shfl_xor(mx, 2));
            mx = fmaxf(mx, __shfl_xor(mx, 4));
            mx = fmaxf(mx, __shfl_xor(mx, 8));
            float sum = 0.f;
#pragma unroll
            for (int tt = 0; tt < 24; tt++) {
                float p = __expf(acc[tt][r] - mx);
                acc[tt][r] = p;
                sum += p;
            }
            sum += __shfl_xor(sum, 1);
            sum += __shfl_xor(sum, 2);
            sum += __shfl_xor(sum, 4);
            sum += __shfl_xor(sum, 8);
            l[r] = sum;
        }
        f32x4 o0 = {0.f, 0.f, 0.f, 0.f}, o1 = {0.f, 0.f, 0.f, 0.f};
        for (int cc = 0; cc < 4; cc++) {
#pragma unroll
            for (int tt6 = 0; tt6 < 6; tt6++) {
                int tt = cc * 6 + tt6;
#pragma unroll
                for (int r = 0; r < 4; r++)
                    Pw[quad * 4 + r][tt6 * 16 + ln] = (unsigned short)f2hs(acc[tt][r]);
            }
#pragma unroll
            for (int kk = 0; kk < 3; kk++) {
                half8 ap = *(const half8*)&Pw[ln][kk * 32 + quad * 8];
                int kg = cc * 96 + kk * 32;
                half8 bv0 = *(const half8*)&Vt[ln][kg + quad * 8];
                half8 bv1 = *(const half8*)&Vt[16 + ln][kg + quad * 8];
                o0 = __builtin_amdgcn_mfma_f32_16x16x32_f16(ap, bv0, o0, 0, 0, 0);
                o1 = __builtin_amdgcn_mfma_f32_16x16x32_f16(ap, bv1, o1, 0, 0, 0);
            }
        }
#pragma unroll
        for (int r = 0; r < 4; r++) {
            int mrow = quad * 4 + r;
            int rw = s * R + q0 + mrow;
            float invl = 1.0f / l[r];
            size_t base = (size_t)rw * E + h * D;
            float g0 = hs2f(gb[base + ln]);
            float g1 = hs2f(gb[base + 16 + ln]);
            og[base + ln]      = o0[r] * invl * g0;
            og[base + 16 + ln] = o1[r] * invl * g1;
        }
    }
}

// ---------------------------------------------------------------------------
// K4: out = og @ wo + bo via split-bf16 MFMA (round-1, verified)
// ---------------------------------------------------------------------------
__global__ __launch_bounds__(256, 2) void k_outproj(
    const float* __restrict__ og, const unsigned short* __restrict__ wot_hi,
    const unsigned short* __restrict__ wot_lo, const float* __restrict__ bo,
    float* __restrict__ out)
{
    __shared__ unsigned int otb[64][260];
    const int t = threadIdx.x;
    const int row0 = blockIdx.x * 64;
#pragma unroll
    for (int i = 0; i < 16; i++) {
        int e4 = i * 256 + t;
        int r = e4 >> 6, c = (e4 & 63) * 4;
        f32x4 v = *(const f32x4*)(og + (size_t)(row0 + r) * E + c);
        u32x4 pk;
        pk[0] = packhl(v[0]); pk[1] = packhl(v[1]);
        pk[2] = packhl(v[2]); pk[3] = packhl(v[3]);
        *(u32x4*)&otb[r][c] = pk;
    }
    __syncthreads();

    const int w = t >> 6, lane = t & 63, ln = lane & 15, quad = lane >> 4;
    const int nbase = w * 64;
    f32x4 acc[4][4];
#pragma unroll
    for (int a = 0; a < 4; a++)
#pragma unroll
        for (int b = 0; b < 4; b++) acc[a][b] = (f32x4){0.f, 0.f, 0.f, 0.f};

    for (int kk = 0; kk < 8; kk++) {
        const int kcol = kk * 32 + quad * 8;
        short8 ah[4], al[4];
#pragma unroll
        for (int mt = 0; mt < 4; mt++) {
            const unsigned int* up = &otb[mt * 16 + ln][kcol];
            u32x4 u0 = *(const u32x4*)up;
            u32x4 u1 = *(const u32x4*)(up + 4);
            U8 A, L;
            A.u[0] = (u0[0] & 0xffffu) | (u0[1] << 16);
            A.u[1] = (u0[2] & 0xffffu) | (u0[3] << 16);
            A.u[2] = (u1[0] & 0xffffu) | (u1[1] << 16);
            A.u[3] = (u1[2] & 0xffffu) | (u1[3] << 16);
            L.u[0] = (u0[0] >> 16) | (u0[1] & 0xffff0000u);
            L.u[1] = (u0[2] >> 16) | (u0[3] & 0xffff0000u);
            L.u[2] = (u1[0] >> 16) | (u1[1] & 0xffff0000u);
            L.u[3] = (u1[2] >> 16) | (u1[3] & 0xffff0000u);
            ah[mt] = A.s; al[mt] = L.s;
        }
#pragma unroll
        for (int nt = 0; nt < 4; nt++) {
            size_t boff = (size_t)(nbase + nt * 16 + ln) * 256 + kcol;
            short8 bh = *(const short8*)(wot_hi + boff);
            short8 bl = *(const short8*)(wot_lo + boff);
#pragma unroll
            for (int mt = 0; mt < 4; mt++) {
                acc[mt][nt] = __builtin_amdgcn_mfma_f32_16x16x32_bf16(ah[mt], bh, acc[mt][nt], 0, 0, 0);
                acc[mt][nt] = __builtin_amdgcn_mfma_f32_16x16x32_bf16(al[mt], bh, acc[mt][nt], 0, 0, 0);
                acc[mt][nt] = __builtin_amdgcn_mfma_f32_16x16x32_bf16(ah[mt], bl, acc[mt][nt], 0, 0, 0);
            }
        }
    }
    const int p = ln & 3;
#pragma unroll
    for (int mt = 0; mt < 4; mt++) {
        int rowg = row0 + mt * 16 + quad * 4 + p;
#pragma unroll
        for (int nt = 0; nt < 4; nt++) {
            int c0 = nbase + nt * 16 + (ln & 12);
            f32x4 a = acc[mt][nt];
            float x0 = a[0], x1 = a[1], x2 = a[2], x3 = a[3];
            xpose4(x0, x1, x2, x3, p);
            float4 bov = *(const float4*)(bo + c0);
            f32x4 o;
            o[0] = x0 + bov.x; o[1] = x1 + bov.y;
            o[2] = x2 + bov.z; o[3] = x3 + bov.w;
            *(f32x4*)(out + (size_t)rowg * CIN + c0) = o;
        }
    }
}

// ---------------------------------------------------------------------------
extern "C" void kernel_launch(void* const* d_in, const int* in_sizes, int n_in,
                              void* d_out, int out_size, void* d_ws, size_t ws_size,
                              hipStream_t stream)
{
    const float* m      = (const float*)d_in[0];
    const float* z      = (const float*)d_in[1];
    const float* mask   = (const float*)d_in[2];
    const float* ln_m_w = (const float*)d_in[3];
    const float* ln_m_b = (const float*)d_in[4];
    const float* ln_z_w = (const float*)d_in[5];
    const float* ln_z_b = (const float*)d_in[6];
    const float* w_pair = (const float*)d_in[7];
    const float* wq     = (const float*)d_in[8];
    const float* wk     = (const float*)d_in[9];
    const float* wv     = (const float*)d_in[10];
    const float* wg     = (const float*)d_in[11];
    const float* bg     = (const float*)d_in[12];
    const float* wo     = (const float*)d_in[13];
    const float* bo     = (const float*)d_in[14];
    float* out = (float*)d_out;

    char* ws = (char*)d_ws;
    float*          pbuf   = (float*)ws;              ws += 4718592;
    unsigned short* qb     = (unsigned short*)ws;     ws += 25165824;
    unsigned short* kb     = (unsigned short*)ws;     ws += 25165824;
    unsigned short* vtb    = (unsigned short*)ws;     ws += 25165824;
    unsigned short* gbuf   = (unsigned short*)ws;     ws += 25165824;
    float*          ogb    = (float*)ws;              ws += 50331648;
    unsigned short* wt_hi  = (unsigned short*)ws;     ws += 524288;
    unsigned short* wt_lo  = (unsigned short*)ws;     ws += 524288;
    unsigned short* wot_hi = (unsigned short*)ws;     ws += 131072;
    unsigned short* wot_lo = (unsigned short*)ws;     ws += 131072;

    k_prepw<<<dim3(320), dim3(256), 0, stream>>>(wq, wk, wv, wg, wo,
                                                 wt_hi, wt_lo, wot_hi, wot_lo);
    k_pairbias<<<dim3(R * R / 4), dim3(256), 0, stream>>>(z, ln_z_w, ln_z_b, w_pair, pbuf);
    k_proj<<<dim3(768), dim3(256), 0, stream>>>(m, ln_m_w, ln_m_b,
                                                wt_hi, wt_lo, bg, qb, kb, vtb, gbuf);
    k_attn<<<dim3(S * H), dim3(256), 0, stream>>>(qb, kb, vtb, gbuf, pbuf, mask, ogb);
    k_outproj<<<dim3(768), dim3(256), 0, stream>>>(ogb, wot_hi, wot_lo, bo, out);
}

// Round 9
// 515.413 us; speedup vs baseline: 1.2301x; 1.0302x over previous
//
#include <hip/hip_runtime.h>
#include <hip/hip_bf16.h>

#define S 128
#define R 384
#define CIN 256
#define H 8
#define D 32
#define CZ 128
#define E 256   // H*D

typedef __attribute__((ext_vector_type(8))) short short8;
typedef __attribute__((ext_vector_type(4))) short short4_;
typedef __attribute__((ext_vector_type(4))) float f32x4;
typedef __attribute__((ext_vector_type(4))) unsigned int u32x4;
typedef __attribute__((ext_vector_type(8))) _Float16 half8;

union U8 { short8 s; unsigned int u[4]; };

__device__ __forceinline__ unsigned short f2bs_u(float f) {
    __hip_bfloat16 h = __float2bfloat16(f);
    return *reinterpret_cast<unsigned short*>(&h);
}
__device__ __forceinline__ short f2bs(float f) {
    __hip_bfloat16 h = __float2bfloat16(f);
    return *reinterpret_cast<short*>(&h);
}
__device__ __forceinline__ float bs2f(unsigned short u) {
    union { unsigned int i; float f; } c;
    c.i = ((unsigned int)u) << 16;
    return c.f;
}
// fp16 bit helpers
__device__ __forceinline__ short f2hs(float f) {
    _Float16 h = (_Float16)f;
    return *reinterpret_cast<short*>(&h);
}
__device__ __forceinline__ float hs2f(unsigned short u) {
    _Float16 h = *reinterpret_cast<_Float16*>(&u);
    return (float)h;
}
// pack f32 -> (hi bf16 in low16, lo bf16 in high16)
__device__ __forceinline__ unsigned int packhl(float x) {
    unsigned short h = f2bs_u(x);
    float rem = x - bs2f(h);
    unsigned short l = f2bs_u(rem);
    return (unsigned int)h | ((unsigned int)l << 16);
}
// 4x4 transpose across 4 lanes (p = lane&3), regs x0..x3
__device__ __forceinline__ void xpose4(float& x0, float& x1, float& x2, float& x3, int p) {
    float tmp;
    if (p & 1) { tmp = x0; x0 = x1; x1 = tmp; tmp = x2; x2 = x3; x3 = tmp; }
    x1 = __shfl_xor(x1, 1); x3 = __shfl_xor(x3, 1);
    if (p & 1) { tmp = x0; x0 = x1; x1 = tmp; tmp = x2; x2 = x3; x3 = tmp; }
    if (p & 2) { tmp = x0; x0 = x2; x2 = tmp; tmp = x1; x1 = x3; x3 = tmp; }
    x2 = __shfl_xor(x2, 2); x3 = __shfl_xor(x3, 2);
    if (p & 2) { tmp = x0; x0 = x2; x2 = tmp; tmp = x1; x1 = x3; x3 = tmp; }
}

// ---------------------------------------------------------------------------
// K0: weight prep. Transpose to e-major and split into bf16 hi/lo. (round-1)
// blocks 0..255: wq/wk/wv/wg -> wt[mat][e][c]; blocks 256..319: wo -> wot[cout][e]
// ---------------------------------------------------------------------------
__global__ __launch_bounds__(256) void k_prepw(
    const float* __restrict__ wq, const float* __restrict__ wk,
    const float* __restrict__ wv, const float* __restrict__ wg,
    const float* __restrict__ wo,
    unsigned short* __restrict__ wt_hi, unsigned short* __restrict__ wt_lo,
    unsigned short* __restrict__ wot_hi, unsigned short* __restrict__ wot_lo)
{
    __shared__ float tl[32][36];
    const int b = blockIdx.x, t = threadIdx.x;
    const int iswo = (b >= 256);
    const int bb = iswo ? (b - 256) : (b & 63);
    const int te = bb >> 3, tc = bb & 7;
    const int mat = b >> 6;
    const float* src = iswo ? wo : (mat == 0 ? wq : mat == 1 ? wk : mat == 2 ? wv : wg);
    unsigned short* dh = iswo ? wot_hi : wt_hi + (size_t)mat * 65536;
    unsigned short* dl = iswo ? wot_lo : wt_lo + (size_t)mat * 65536;

    const int r = t >> 3, c4 = (t & 7) * 4;
    float4 v = *(const float4*)(src + (size_t)(tc * 32 + r) * 256 + te * 32 + c4);
    tl[r][c4] = v.x; tl[r][c4 + 1] = v.y; tl[r][c4 + 2] = v.z; tl[r][c4 + 3] = v.w;
    __syncthreads();
    short4_ hv, lv;
#pragma unroll
    for (int j = 0; j < 4; j++) {
        float x = tl[c4 + j][r];
        unsigned short hb = f2bs_u(x);
        hv[j] = (short)hb;
        lv[j] = f2bs(x - bs2f(hb));
    }
    size_t o = (size_t)(te * 32 + r) * 256 + tc * 32 + c4;
    *(short4_*)(dh + o) = hv;
    *(short4_*)(dl + o) = lv;
}

// ---------------------------------------------------------------------------
// K1: pair bias (f32, unchanged)
// ---------------------------------------------------------------------------
__global__ __launch_bounds__(256) void k_pairbias(
    const float* __restrict__ z, const float* __restrict__ lnw,
    const float* __restrict__ lnb, const float* __restrict__ wp,
    float* __restrict__ pb)
{
    int wid  = blockIdx.x * 4 + (threadIdx.x >> 6);
    int lane = threadIdx.x & 63;
    int qi = wid / R;
    int ki = wid - qi * R;
    const float* zr = z + (size_t)wid * CZ;
    float z0 = zr[lane], z1 = zr[lane + 64];
    float s  = z0 + z1;
    float sq = z0 * z0 + z1 * z1;
#pragma unroll
    for (int off = 32; off >= 1; off >>= 1) {
        s  += __shfl_xor(s, off);
        sq += __shfl_xor(sq, off);
    }
    float mu   = s * (1.0f / CZ);
    float var  = sq * (1.0f / CZ) - mu * mu;
    float rstd = rsqrtf(var + 1e-5f);
    float zl0 = (z0 - mu) * rstd * lnw[lane]      + lnb[lane];
    float zl1 = (z1 - mu) * rstd * lnw[lane + 64] + lnb[lane + 64];
    const float* w0 = wp + lane * H;
    const float* w1 = wp + (lane + 64) * H;
    float ph[H];
#pragma unroll
    for (int h = 0; h < H; h++) ph[h] = zl0 * w0[h] + zl1 * w1[h];
#pragma unroll
    for (int off = 32; off >= 1; off >>= 1) {
#pragma unroll
        for (int h = 0; h < H; h++) ph[h] += __shfl_xor(ph[h], off);
    }
    if (lane == 0) {
#pragma unroll
        for (int h = 0; h < H; h++)
            pb[((size_t)h * R + qi) * R + ki] = ph[h];
    }
}

// ---------------------------------------------------------------------------
// K2 v9: r1 NUMERICS + r4 STRUCTURE (512 threads, 8 waves, wave=(mat,nc-half))
// but with __launch_bounds__(512, 2): min-waves 2/EU caps VGPR at 256 (r4's
// LB(512,4) capped at 128 -> compiler chose 64 -> 280 MB spill). Per-wave
// inner loop is byte-identical to r1's (which allocates 108 VGPR, no spill);
// LDS 68 KB -> 2 blocks/CU = 16 waves/CU (2x r1's latency-hiding pool).
// Correctness of this wave decomposition proven in r4 (absmax 1.220703e-4).
// ---------------------------------------------------------------------------
__global__ __launch_bounds__(512, 2) void k_proj(
    const float* __restrict__ m, const float* __restrict__ lnw,
    const float* __restrict__ lnb,
    const unsigned short* __restrict__ wt_hi, const unsigned short* __restrict__ wt_lo,
    const float* __restrict__ bg,
    unsigned short* __restrict__ qb, unsigned short* __restrict__ kb,
    unsigned short* __restrict__ vtb, unsigned short* __restrict__ gb)
{
    __shared__ unsigned short Ah[64][264];
    __shared__ unsigned short Al[64][264];
    __shared__ float muv[64][2];
    const int t = threadIdx.x;
    const int row0 = blockIdx.x * 64;
    const int sblk = blockIdx.x / 6;
    const int res0 = (blockIdx.x % 6) * 64;

    // pass 1: LN stats, 2 threads per row (partners adjacent in wave)
    if (t < 128) {
        int r = t >> 1, half = t & 1;
        const float* mr = m + (size_t)(row0 + r) * CIN + half * 128;
        float s = 0.f, sq = 0.f;
#pragma unroll
        for (int i = 0; i < 32; i++) {
            f32x4 v = *(const f32x4*)(mr + i * 4);
#pragma unroll
            for (int q = 0; q < 4; q++) { s += v[q]; sq += v[q] * v[q]; }
        }
        s  += __shfl_xor(s, 1);
        sq += __shfl_xor(sq, 1);
        if (half == 0) {
            float mu  = s * (1.0f / CIN);
            float var = sq * (1.0f / CIN) - mu * mu;
            muv[r][0] = mu;
            muv[r][1] = rsqrtf(var + 1e-5f);
        }
    }
    __syncthreads();
    // pass 2: normalize + bf16 hi/lo -> LDS planes
#pragma unroll
    for (int i = 0; i < 8; i++) {
        int idx = i * 512 + t;
        int r = idx >> 6, c4 = (idx & 63) * 4;
        f32x4 v = *(const f32x4*)(m + (size_t)(row0 + r) * CIN + c4);
        float4 lw = *(const float4*)(lnw + c4);
        float4 lb = *(const float4*)(lnb + c4);
        float mu = muv[r][0], rs = muv[r][1];
        short4_ oh, ol;
#pragma unroll
        for (int j = 0; j < 4; j++) {
            float lwj = (j == 0) ? lw.x : (j == 1) ? lw.y : (j == 2) ? lw.z : lw.w;
            float lbj = (j == 0) ? lb.x : (j == 1) ? lb.y : (j == 2) ? lb.z : lb.w;
            float x = (v[j] - mu) * rs * lwj + lbj;
            unsigned short hb = f2bs_u(x);
            oh[j] = (short)hb;
            ol[j] = f2bs(x - bs2f(hb));
        }
        *(short4_*)&Ah[r][c4] = oh;
        *(short4_*)&Al[r][c4] = ol;
    }
    __syncthreads();

    const int w2 = t >> 6;           // 0..7
    const int mat = w2 & 3;          // which weight matrix
    const int nch = w2 >> 2;         // nc half: 0 -> nc{0,1}, 1 -> nc{2,3}
    const int lane = t & 63, ln = lane & 15, quad = lane >> 4;
    const unsigned short* Bh = wt_hi + (size_t)mat * 65536;
    const unsigned short* Bl = wt_lo + (size_t)mat * 65536;

    for (int nci = 0; nci < 2; nci++) {
        const int nc = nch * 2 + nci;
        const int nbase = nc * 64;
        f32x4 acc[4][4];
#pragma unroll
        for (int a = 0; a < 4; a++)
#pragma unroll
            for (int b = 0; b < 4; b++) acc[a][b] = (f32x4){0.f, 0.f, 0.f, 0.f};

#pragma unroll 2
        for (int kk = 0; kk < 8; kk++) {
            const int kcol = kk * 32 + quad * 8;
            short8 ah[4], al[4];
#pragma unroll
            for (int mt = 0; mt < 4; mt++) {
                ah[mt] = *(const short8*)&Ah[mt * 16 + ln][kcol];
                al[mt] = *(const short8*)&Al[mt * 16 + ln][kcol];
            }
#pragma unroll
            for (int nt = 0; nt < 4; nt++) {
                size_t boff = (size_t)(nbase + nt * 16 + ln) * 256 + kcol;
                short8 bh = *(const short8*)(Bh + boff);
                short8 bl = *(const short8*)(Bl + boff);
#pragma unroll
                for (int mt = 0; mt < 4; mt++) {
                    acc[mt][nt] = __builtin_amdgcn_mfma_f32_16x16x32_bf16(ah[mt], bh, acc[mt][nt], 0, 0, 0);
                    acc[mt][nt] = __builtin_amdgcn_mfma_f32_16x16x32_bf16(al[mt], bh, acc[mt][nt], 0, 0, 0);
                    acc[mt][nt] = __builtin_amdgcn_mfma_f32_16x16x32_bf16(ah[mt], bl, acc[mt][nt], 0, 0, 0);
                }
            }
        }
        // epilogue (outputs fp16)
        if (mat == 2) {
            // V: C-layout is res-contiguous per lane -> vt[h][d][res]
#pragma unroll
            for (int mt = 0; mt < 4; mt++) {
                int resg = res0 + mt * 16 + quad * 4;
#pragma unroll
                for (int nt = 0; nt < 4; nt++) {
                    int e = nbase + nt * 16 + ln;
                    int hh = e >> 5, d = e & 31;
                    f32x4 a = acc[mt][nt];
                    short4_ vv;
                    vv[0] = f2hs(a[0]); vv[1] = f2hs(a[1]);
                    vv[2] = f2hs(a[2]); vv[3] = f2hs(a[3]);
                    *(short4_*)(vtb + (((size_t)(sblk * H + hh)) * D + d) * R + resg) = vv;
                }
            }
        } else if (mat == 3) {
            const int p = ln & 3;
#pragma unroll
            for (int mt = 0; mt < 4; mt++) {
                int rowg = row0 + mt * 16 + quad * 4 + p;
#pragma unroll
                for (int nt = 0; nt < 4; nt++) {
                    int e0 = nbase + nt * 16 + (ln & 12);
                    f32x4 a = acc[mt][nt];
                    float x0 = a[0], x1 = a[1], x2 = a[2], x3 = a[3];
                    xpose4(x0, x1, x2, x3, p);
                    float4 bgv = *(const float4*)(bg + e0);
                    short4_ gv;
                    gv[0] = f2hs(1.0f / (1.0f + __expf(-(x0 + bgv.x))));
                    gv[1] = f2hs(1.0f / (1.0f + __expf(-(x1 + bgv.y))));
                    gv[2] = f2hs(1.0f / (1.0f + __expf(-(x2 + bgv.z))));
                    gv[3] = f2hs(1.0f / (1.0f + __expf(-(x3 + bgv.w))));
                    *(short4_*)(gb + (size_t)rowg * E + e0) = gv;
                }
            }
        } else {
            const float sc = (mat == 0) ? 0.17677669529663687f : 1.0f;
            unsigned short* dst = (mat == 0) ? qb : kb;
            const int p = ln & 3;
#pragma unroll
            for (int mt = 0; mt < 4; mt++) {
                int resg = res0 + mt * 16 + quad * 4 + p;
#pragma unroll
                for (int nt = 0; nt < 4; nt++) {
                    int e0 = nbase + nt * 16 + (ln & 12);
                    f32x4 a = acc[mt][nt];
                    float x0 = a[0] * sc, x1 = a[1] * sc, x2 = a[2] * sc, x3 = a[3] * sc;
                    xpose4(x0, x1, x2, x3, p);
                    int hh = e0 >> 5, d0 = e0 & 31;
                    short4_ vv;
                    vv[0] = f2hs(x0); vv[1] = f2hs(x1); vv[2] = f2hs(x2); vv[3] = f2hs(x3);
                    *(short4_*)(dst + (((size_t)(sblk * H + hh)) * R + resg) * D + d0) = vv;
                }
            }
        }
    }
}

// ---------------------------------------------------------------------------
// K3: MFMA attention — fp16 operands; P stored in LDS as fp16 (value-identical,
// LDS 69.1 KB -> 2 blocks/CU). Verified passing in r8.
// ---------------------------------------------------------------------------
__global__ __launch_bounds__(256, 2) void k_attn(
    const unsigned short* __restrict__ qb, const unsigned short* __restrict__ kb,
    const unsigned short* __restrict__ vtb, const unsigned short* __restrict__ gb,
    const float* __restrict__ pb, const float* __restrict__ mask,
    float* __restrict__ og)
{
    __shared__ unsigned short Ks[R][40];
    __shared__ unsigned short Vt[D][392];
    __shared__ unsigned short Ps[4][16][104];   // fp16 P, 96 used + 8 pad
    const int t = threadIdx.x;
    const int s = blockIdx.x >> 3;
    const int h = blockIdx.x & 7;
    const size_t kvbase = (size_t)(s * H + h) * R * D;

#pragma unroll
    for (int i = 0; i < 6; i++) {
        int idx = i * 256 + t;
        int res = idx >> 2, d = (idx & 3) * 8;
        *(short8*)&Ks[res][d] = *(const short8*)(kb + kvbase + (size_t)res * D + d);
    }
#pragma unroll
    for (int i = 0; i < 6; i++) {
        int idx = i * 256 + t;
        int d = idx / 48, j = idx - d * 48;
        *(short8*)&Vt[d][j * 8] = *(const short8*)(vtb + kvbase + (size_t)d * R + j * 8);
    }
    __syncthreads();

    const int w = t >> 6;
    const int lane = t & 63;
    const int ln = lane & 15;
    const int quad = lane >> 4;
    unsigned short (*Pw)[104] = Ps[w];

    float mr[24];
#pragma unroll
    for (int tt = 0; tt < 24; tt++)
        mr[tt] = 1e9f * (mask[s * R + tt * 16 + ln] - 1.0f);

    for (int qt = 0; qt < 6; qt++) {
        const int q0 = w * 96 + qt * 16;
        half8 aq = *(const half8*)(qb + kvbase + (size_t)(q0 + ln) * D + quad * 8);
        const float* pbrow = pb + ((size_t)h * R + q0 + quad * 4) * R + ln;

        f32x4 acc[24];
#pragma unroll
        for (int tt = 0; tt < 24; tt++) {
            f32x4 c;
#pragma unroll
            for (int r = 0; r < 4; r++)
                c[r] = pbrow[(size_t)r * R + tt * 16] + mr[tt];
            half8 bk = *(const half8*)&Ks[tt * 16 + ln][quad * 8];
            acc[tt] = __builtin_amdgcn_mfma_f32_16x16x32_f16(aq, bk, c, 0, 0, 0);
        }
        float l[4];
#pragma unroll
        for (int r = 0; r < 4; r++) {
            float mx = acc[0][r];
#pragma unroll
            for (int tt = 1; tt < 24; tt++) mx = fmaxf(mx, acc[tt][r]);
            mx = fmaxf(mx, __shfl_xor(mx, 1));
            mx = fmaxf(mx, __shfl_xor(mx, 2));
            mx = fmaxf(mx, __shfl_xor(mx, 4));
            mx = fmaxf(mx, __shfl_xor(mx, 8));
            float sum = 0.f;
#pragma unroll
            for (int tt = 0; tt < 24; tt++) {
                float p = __expf(acc[tt][r] - mx);
                acc[tt][r] = p;
                sum += p;
            }
            sum += __shfl_xor(sum, 1);
            sum += __shfl_xor(sum, 2);
            sum += __shfl_xor(sum, 4);
            sum += __shfl_xor(sum, 8);
            l[r] = sum;
        }
        f32x4 o0 = {0.f, 0.f, 0.f, 0.f}, o1 = {0.f, 0.f, 0.f, 0.f};
        for (int cc = 0; cc < 4; cc++) {
#pragma unroll
            for (int tt6 = 0; tt6 < 6; tt6++) {
                int tt = cc * 6 + tt6;
#pragma unroll
                for (int r = 0; r < 4; r++)
                    Pw[quad * 4 + r][tt6 * 16 + ln] = (unsigned short)f2hs(acc[tt][r]);
            }
#pragma unroll
            for (int kk = 0; kk < 3; kk++) {
                half8 ap = *(const half8*)&Pw[ln][kk * 32 + quad * 8];
                int kg = cc * 96 + kk * 32;
                half8 bv0 = *(const half8*)&Vt[ln][kg + quad * 8];
                half8 bv1 = *(const half8*)&Vt[16 + ln][kg + quad * 8];
                o0 = __builtin_amdgcn_mfma_f32_16x16x32_f16(ap, bv0, o0, 0, 0, 0);
                o1 = __builtin_amdgcn_mfma_f32_16x16x32_f16(ap, bv1, o1, 0, 0, 0);
            }
        }
#pragma unroll
        for (int r = 0; r < 4; r++) {
            int mrow = quad * 4 + r;
            int rw = s * R + q0 + mrow;
            float invl = 1.0f / l[r];
            size_t base = (size_t)rw * E + h * D;
            float g0 = hs2f(gb[base + ln]);
            float g1 = hs2f(gb[base + 16 + ln]);
            og[base + ln]      = o0[r] * invl * g0;
            og[base + 16 + ln] = o1[r] * invl * g1;
        }
    }
}

// ---------------------------------------------------------------------------
// K4: out = og @ wo + bo via split-bf16 MFMA (round-1, verified)
// ---------------------------------------------------------------------------
__global__ __launch_bounds__(256, 2) void k_outproj(
    const float* __restrict__ og, const unsigned short* __restrict__ wot_hi,
    const unsigned short* __restrict__ wot_lo, const float* __restrict__ bo,
    float* __restrict__ out)
{
    __shared__ unsigned int otb[64][260];
    const int t = threadIdx.x;
    const int row0 = blockIdx.x * 64;
#pragma unroll
    for (int i = 0; i < 16; i++) {
        int e4 = i * 256 + t;
        int r = e4 >> 6, c = (e4 & 63) * 4;
        f32x4 v = *(const f32x4*)(og + (size_t)(row0 + r) * E + c);
        u32x4 pk;
        pk[0] = packhl(v[0]); pk[1] = packhl(v[1]);
        pk[2] = packhl(v[2]); pk[3] = packhl(v[3]);
        *(u32x4*)&otb[r][c] = pk;
    }
    __syncthreads();

    const int w = t >> 6, lane = t & 63, ln = lane & 15, quad = lane >> 4;
    const int nbase = w * 64;
    f32x4 acc[4][4];
#pragma unroll
    for (int a = 0; a < 4; a++)
#pragma unroll
        for (int b = 0; b < 4; b++) acc[a][b] = (f32x4){0.f, 0.f, 0.f, 0.f};

    for (int kk = 0; kk < 8; kk++) {
        const int kcol = kk * 32 + quad * 8;
        short8 ah[4], al[4];
#pragma unroll
        for (int mt = 0; mt < 4; mt++) {
            const unsigned int* up = &otb[mt * 16 + ln][kcol];
            u32x4 u0 = *(const u32x4*)up;
            u32x4 u1 = *(const u32x4*)(up + 4);
            U8 A, L;
            A.u[0] = (u0[0] & 0xffffu) | (u0[1] << 16);
            A.u[1] = (u0[2] & 0xffffu) | (u0[3] << 16);
            A.u[2] = (u1[0] & 0xffffu) | (u1[1] << 16);
            A.u[3] = (u1[2] & 0xffffu) | (u1[3] << 16);
            L.u[0] = (u0[0] >> 16) | (u0[1] & 0xffff0000u);
            L.u[1] = (u0[2] >> 16) | (u0[3] & 0xffff0000u);
            L.u[2] = (u1[0] >> 16) | (u1[1] & 0xffff0000u);
            L.u[3] = (u1[2] >> 16) | (u1[3] & 0xffff0000u);
            ah[mt] = A.s; al[mt] = L.s;
        }
#pragma unroll
        for (int nt = 0; nt < 4; nt++) {
            size_t boff = (size_t)(nbase + nt * 16 + ln) * 256 + kcol;
            short8 bh = *(const short8*)(wot_hi + boff);
            short8 bl = *(const short8*)(wot_lo + boff);
#pragma unroll
            for (int mt = 0; mt < 4; mt++) {
                acc[mt][nt] = __builtin_amdgcn_mfma_f32_16x16x32_bf16(ah[mt], bh, acc[mt][nt], 0, 0, 0);
                acc[mt][nt] = __builtin_amdgcn_mfma_f32_16x16x32_bf16(al[mt], bh, acc[mt][nt], 0, 0, 0);
                acc[mt][nt] = __builtin_amdgcn_mfma_f32_16x16x32_bf16(ah[mt], bl, acc[mt][nt], 0, 0, 0);
            }
        }
    }
    const int p = ln & 3;
#pragma unroll
    for (int mt = 0; mt < 4; mt++) {
        int rowg = row0 + mt * 16 + quad * 4 + p;
#pragma unroll
        for (int nt = 0; nt < 4; nt++) {
            int c0 = nbase + nt * 16 + (ln & 12);
            f32x4 a = acc[mt][nt];
            float x0 = a[0], x1 = a[1], x2 = a[2], x3 = a[3];
            xpose4(x0, x1, x2, x3, p);
            float4 bov = *(const float4*)(bo + c0);
            f32x4 o;
            o[0] = x0 + bov.x; o[1] = x1 + bov.y;
            o[2] = x2 + bov.z; o[3] = x3 + bov.w;
            *(f32x4*)(out + (size_t)rowg * CIN + c0) = o;
        }
    }
}

// ---------------------------------------------------------------------------
extern "C" void kernel_launch(void* const* d_in, const int* in_sizes, int n_in,
                              void* d_out, int out_size, void* d_ws, size_t ws_size,
                              hipStream_t stream)
{
    const float* m      = (const float*)d_in[0];
    const float* z      = (const float*)d_in[1];
    const float* mask   = (const float*)d_in[2];
    const float* ln_m_w = (const float*)d_in[3];
    const float* ln_m_b = (const float*)d_in[4];
    const float* ln_z_w = (const float*)d_in[5];
    const float* ln_z_b = (const float*)d_in[6];
    const float* w_pair = (const float*)d_in[7];
    const float* wq     = (const float*)d_in[8];
    const float* wk     = (const float*)d_in[9];
    const float* wv     = (const float*)d_in[10];
    const float* wg     = (const float*)d_in[11];
    const float* bg     = (const float*)d_in[12];
    const float* wo     = (const float*)d_in[13];
    const float* bo     = (const float*)d_in[14];
    float* out = (float*)d_out;

    char* ws = (char*)d_ws;
    float*          pbuf   = (float*)ws;              ws += 4718592;
    unsigned short* qb     = (unsigned short*)ws;     ws += 25165824;
    unsigned short* kb     = (unsigned short*)ws;     ws += 25165824;
    unsigned short* vtb    = (unsigned short*)ws;     ws += 25165824;
    unsigned short* gbuf   = (unsigned short*)ws;     ws += 25165824;
    float*          ogb    = (float*)ws;              ws += 50331648;
    unsigned short* wt_hi  = (unsigned short*)ws;     ws += 524288;
    unsigned short* wt_lo  = (unsigned short*)ws;     ws += 524288;
    unsigned short* wot_hi = (unsigned short*)ws;     ws += 131072;
    unsigned short* wot_lo = (unsigned short*)ws;     ws += 131072;

    k_prepw<<<dim3(320), dim3(256), 0, stream>>>(wq, wk, wv, wg, wo,
                                                 wt_hi, wt_lo, wot_hi, wot_lo);
    k_pairbias<<<dim3(R * R / 4), dim3(256), 0, stream>>>(z, ln_z_w, ln_z_b, w_pair, pbuf);
    k_proj<<<dim3(768), dim3(512), 0, stream>>>(m, ln_m_w, ln_m_b,
                                                wt_hi, wt_lo, bg, qb, kb, vtb, gbuf);
    k_attn<<<dim3(S * H), dim3(256), 0, stream>>>(qb, kb, vtb, gbuf, pbuf, mask, ogb);
    k_outproj<<<dim3(768), dim3(256), 0, stream>>>(ogb, wot_hi, wot_lo, bo, out);
}